// Round 2
// baseline (21386.176 us; speedup 1.0000x reference)
//
#include <hip/hip_runtime.h>
#include <stdint.h>

typedef unsigned long long u64;
typedef uint32_t u32;

#define NB     256
#define NT     256
#define TMAX   2048
#define EPROJS 1024
#define DUNITS 512
#define EMBED  512
#define JOINT  512
#define ODIM   10000

#define N_LSTM 32          // blocks 0..31: LSTM + row-partitioned u producers
#define CONS0  32          // blocks 32..254: consumers (W_out)
#define N_CONS 223
#define AGG_B  255         // block 255: score/token aggregator
#define MAGIC  0xD07ED07Eu

// workspace layout (bytes); first 32 KB zeroed by rnnt_init
#define WS_Y    0          // float[2][512]   y state, parity-buffered
#define WS_U    4096       // float[2][512]   u = W_dec@y, parity-buffered (plain stores)
#define WS_PK   8192       // u64[4][224]     consumer packs, 4-deep ring
#define WS_SA   15360      // u64[4][224]     consumer sum-exp, 4-deep ring
#define WS_DN   22528      // u32[256]        setup-done flags
#define WS_CNT  23552      // u32 y-epoch counter replicas [8] @ 128B stride
#define WS_CNT2 24576      // u32 u-epoch counter replicas [8] @ 128B stride
#define WS_HP   32768      // float[2048][512] h_proj  (4 MB)

__device__ __forceinline__ float aloadf(const float* p){
  return __hip_atomic_load(p, __ATOMIC_RELAXED, __HIP_MEMORY_SCOPE_AGENT);
}
__device__ __forceinline__ void astoref(float* p, float v){
  __hip_atomic_store(p, v, __ATOMIC_RELAXED, __HIP_MEMORY_SCOPE_AGENT);
}
__device__ __forceinline__ u64 aloadu64(const u64* p){
  return __hip_atomic_load(p, __ATOMIC_RELAXED, __HIP_MEMORY_SCOPE_AGENT);
}
__device__ __forceinline__ void astoreu64(u64* p, u64 v){
  __hip_atomic_store(p, v, __ATOMIC_RELAXED, __HIP_MEMORY_SCOPE_AGENT);
}
__device__ __forceinline__ u32 aloadu32(const u32* p){
  return __hip_atomic_load(p, __ATOMIC_RELAXED, __HIP_MEMORY_SCOPE_AGENT);
}
__device__ __forceinline__ void astoreu32(u32* p, u32 v){
  __hip_atomic_store(p, v, __ATOMIC_RELAXED, __HIP_MEMORY_SCOPE_AGENT);
}

__device__ __forceinline__ u32 ordbits(float f){
  u32 u = __float_as_uint(f);
  return (u & 0x80000000u) ? ~u : (u | 0x80000000u);
}
__device__ __forceinline__ float unordbits(u32 o){
  u32 u = (o & 0x80000000u) ? (o & 0x7fffffffu) : ~o;
  return __uint_as_float(u);
}
__device__ __forceinline__ float sigmoidf_(float x){ return 1.0f/(1.0f+expf(-x)); }

__device__ __forceinline__ float wredsum(float v){
  #pragma unroll
  for (int o=32;o>0;o>>=1) v += __shfl_xor(v, o);
  return v;
}
__device__ __forceinline__ u64 wredmax64(u64 v){
  #pragma unroll
  for (int o=32;o>0;o>>=1){ u64 x = __shfl_xor(v, o); v = (x>v)?x:v; }
  return v;
}

#define LOAD8(dst, baseptr) { const float4* _p=(const float4*)(baseptr); \
  float4 _a=_p[0], _b=_p[1]; \
  dst[0]=_a.x; dst[1]=_a.y; dst[2]=_a.z; dst[3]=_a.w; \
  dst[4]=_b.x; dst[5]=_b.y; dst[6]=_b.z; dst[7]=_b.w; }

__global__ void rnnt_init(char* ws){
  // zero the 32 KB control region (state buffers, rings, flags, counters)
  u32* p = (u32*)ws;
  for (int i = threadIdx.x; i < 8192; i += blockDim.x) p[i] = 0u;
}

__global__ void __launch_bounds__(NT, 1)
rnnt_decode(const float* __restrict__ h,    const float* __restrict__ embed,
            const float* __restrict__ W_ih, const float* __restrict__ W_hh,
            const float* __restrict__ b_ih, const float* __restrict__ b_hh,
            const float* __restrict__ W_enc,const float* __restrict__ b_enc,
            const float* __restrict__ W_dec,const float* __restrict__ W_out,
            const float* __restrict__ b_out,
            float* __restrict__ out, char* __restrict__ ws)
{
  const int b    = blockIdx.x;
  const int tid  = threadIdx.x;
  const int lane = tid & 63;
  const int w    = tid >> 6;

  float* ybuf = (float*)(ws + WS_Y);
  u64*  pkall = (u64*)(ws + WS_PK);
  u64*  saall = (u64*)(ws + WS_SA);
  u32*  done  = (u32*)(ws + WS_DN);
  u32*  cnt   = (u32*)(ws + WS_CNT);
  u32*  cnt2  = (u32*)(ws + WS_CNT2);
  float* hp   = (float*)(ws + WS_HP);

  __shared__ float smem[8192];                 // 32 KB, multi-purpose
  float* PL = smem;                            // [64][68] partial sums
  float* GL = &smem[4416];                     // gates   (64)
  u64*   R64= (u64*)&smem[4480];               // 4 u64 reduce slots
  float* RF = &smem[4488];                     // 4 float reduce slots

  // ================= setup: hp = h @ W_enc^T + b_enc (rows 8b..8b+7) =========
  {
    float (*lds_h)[EPROJS] = (float(*)[EPROJS])smem;
    #pragma unroll
    for (int r=0;r<8;r++){
      const float4 hv = *(const float4*)(h + (size_t)(8*b + r)*EPROJS + tid*4);
      *(float4*)&lds_h[r][tid*4] = hv;
    }
    __syncthreads();
    for (int p=0;p<2;p++){
      const int j = p*NT + tid;
      float acc[8] = {0,0,0,0,0,0,0,0};
      const float4* wrow = (const float4*)(W_enc + (size_t)j*EPROJS);
      for (int k4=0;k4<EPROJS/4;k4++){
        const float4 wv = wrow[k4];
        #pragma unroll
        for (int t8=0;t8<8;t8++){
          const float4 hv = *(const float4*)&lds_h[t8][k4*4];
          acc[t8] = fmaf(wv.x,hv.x, fmaf(wv.y,hv.y, fmaf(wv.z,hv.z, fmaf(wv.w,hv.w, acc[t8]))));
        }
      }
      const float be = b_enc[j];
      #pragma unroll
      for (int t8=0;t8<8;t8++)
        astoref(&hp[(size_t)(8*b+t8)*JOINT + j], acc[t8] + be);
    }
    asm volatile("s_waitcnt vmcnt(0)" ::: "memory");
    if (tid==0) astoreu32(&done[b], MAGIC);
    __syncthreads();   // smem reuse fence
  }

  // ============================ role: LSTM + u-rows ==========================
  if (b < N_LSTM){
    const int d = b;
    float wih[16][8], whh[16][8];
    #pragma unroll
    for (int q=0;q<16;q++){
      const int gr = w*DUNITS + 16*d + q;       // wave w = gate type (i,f,g,o)
      LOAD8(wih[q], W_ih + (size_t)gr*EMBED  + lane*8);
      LOAD8(whh[q], W_hh + (size_t)gr*DUNITS + lane*8);
    }
    // W_dec ROW slice: wave w owns rows 16d+4w .. 16d+4w+3 (full 512-wide)
    float wdr[4][8];
    #pragma unroll
    for (int i=0;i<4;i++){
      const int r = 16*d + 4*w + i;
      LOAD8(wdr[i], W_dec + (size_t)r*DUNITS + 8*lane);
    }
    float bias_r = 0.0f;
    if (tid < 64){
      const int gr = (tid>>4)*DUNITS + 16*d + (tid&15);
      bias_r = b_ih[gr] + b_hh[gr];
    }
    // bootstrap state -> publish y(1) (parity 1)
    float c_st = 0.0f, y_st = 0.0f;
    if (tid < 16){
      const int j = 16*d + tid;
      const float gi = b_ih[j]            + b_hh[j];
      const float gg = b_ih[2*DUNITS + j] + b_hh[2*DUNITS + j];
      const float go = b_ih[3*DUNITS + j] + b_hh[3*DUNITS + j];
      c_st = sigmoidf_(gi)*tanhf(gg);
      y_st = sigmoidf_(go)*tanhf(c_st);
      astoref(&ybuf[512 + j], y_st);
    }
    asm volatile("s_waitcnt vmcnt(0)" ::: "memory");
    if (tid < 8) atomicAdd(&cnt[tid*32], 1u);   // storers+adders are wave 0

    for (int t=0;t<TMAX;t++){
      const u32 g = (u32)(t+1);
      // --- wait y(g) complete ---
      if (tid==0){ while (aloadu32(&cnt[(d&7)*32]) < 32u*g) {} }
      __syncthreads();
      // --- direct per-lane y(g) gather (L1-bypassing) ---
      float y8[8];
      {
        const u64* yb = (const u64*)(ws + WS_Y + (size_t)(g&1)*2048);
        #pragma unroll
        for (int i=0;i<4;i++){
          const u64 v = aloadu64(&yb[4*lane + i]);
          y8[2*i]   = __uint_as_float((u32)v);
          y8[2*i+1] = __uint_as_float((u32)(v>>32));
        }
      }
      // --- u rows (16d+4w+i) = W_dec rows @ y, publish ASAP ---
      {
        float p0=0.f,p1=0.f,p2=0.f,p3=0.f;
        #pragma unroll
        for (int k=0;k<8;k++){
          p0 = fmaf(wdr[0][k], y8[k], p0);
          p1 = fmaf(wdr[1][k], y8[k], p1);
          p2 = fmaf(wdr[2][k], y8[k], p2);
          p3 = fmaf(wdr[3][k], y8[k], p3);
        }
        #pragma unroll
        for (int o=32;o>0;o>>=1){
          p0 += __shfl_xor(p0,o); p1 += __shfl_xor(p1,o);
          p2 += __shfl_xor(p2,o); p3 += __shfl_xor(p3,o);
        }
        if (lane==0){
          float* up = (float*)(ws + WS_U + (size_t)(g&1)*2048) + 16*d + 4*w;
          astoref(&up[0],p0); astoref(&up[1],p1);
          astoref(&up[2],p2); astoref(&up[3],p3);
        }
      }
      asm volatile("s_waitcnt vmcnt(0)" ::: "memory");
      __syncthreads();                           // all 4 waves' u stores drained
      if (tid < 8) atomicAdd(&cnt2[tid*32], 1u);
      // --- vp = W_hh @ y partials (hidden under pack wait) ---
      float vp[16];
      #pragma unroll
      for (int q=0;q<16;q++){
        float a=0.f;
        #pragma unroll
        for (int k=0;k<8;k++) a = fmaf(whh[q][k], y8[k], a);
        vp[q] = a;
      }
      // --- poll packs(g), per-wave subsets ---
      u64 pk = 0;
      {
        const u64* pks = pkall + (g&3)*224;
        for(;;){
          pk = (tid < N_CONS) ? aloadu64(&pks[tid]) : 0;
          const int ok = (tid < N_CONS) ? ((u32)(pk>>48) >= g) : 1;
          if (__all(ok)) break;
        }
      }
      const u64 m = wredmax64(pk);
      if (lane==0) R64[w] = m;
      // speculative embed prefetch of this wave's candidate (warms L1 too)
      const int predw = (int)((~(u32)m) & 0xFFFFu);
      float e8[8];
      LOAD8(e8, embed + (size_t)predw*EMBED + 8*lane);
      __syncthreads();
      u64 best = R64[0];
      #pragma unroll
      for (int i=1;i<4;i++){ const u64 x=R64[i]; best = (x>best)?x:best; }
      const int pred = (int)((~(u32)best) & 0xFFFFu);
      const int emitted = (pred != 0);
      if (m != best){                            // wave-uniform mispredict: L1-hot reload
        LOAD8(e8, embed + (size_t)pred*EMBED + 8*lane);
      }
      #pragma unroll
      for (int q=0;q<16;q++){
        float a = vp[q];
        #pragma unroll
        for (int k=0;k<8;k++) a = fmaf(wih[q][k], e8[k], a);
        PL[(w*16+q)*68 + lane] = a;
      }
      __syncthreads();
      if (tid < 64){
        const float* row = &PL[tid*68];
        float s = bias_r;
        #pragma unroll
        for (int k4=0;k4<16;k4++){
          const float4 v4 = *(const float4*)&row[4*k4];
          s += v4.x + v4.y + v4.z + v4.w;
        }
        GL[tid] = s;
      }
      __syncthreads();
      if (tid < 16){
        const float gi=GL[tid], gf=GL[16+tid], gg=GL[32+tid], go=GL[48+tid];
        const float cn = sigmoidf_(gf)*c_st + sigmoidf_(gi)*tanhf(gg);
        const float yn = sigmoidf_(go)*tanhf(cn);
        if (emitted){ c_st = cn; y_st = yn; }
        astoref(&ybuf[((g+1)&1)*512 + 16*d + tid], y_st);
      }
      asm volatile("s_waitcnt vmcnt(0)" ::: "memory");
      if (t < TMAX-1 && tid < 8) atomicAdd(&cnt[tid*32], 1u);
      // next-iteration post-poll barrier fences PL/GL reuse
    }
  }
  // ============================ role: CONSUMER ===============================
  else if (b < AGG_B){
    const int cb = b - CONS0;
    int rowstart, rowcnt;
    if (cb < 188){ rowstart = cb*45;                 rowcnt = 45; }
    else         { rowstart = 8460 + (cb-188)*44;    rowcnt = 44; }
    float wout[12][8];
    #pragma unroll
    for (int q=0;q<12;q++){
      const int s = 12*w + q;
      if (s < rowcnt){
        LOAD8(wout[q], W_out + (size_t)(rowstart+s)*JOINT + lane*8);
      } else {
        #pragma unroll
        for (int k=0;k<8;k++) wout[q][k]=0.f;
      }
    }
    float my_bo = 0.f; int my_row = 0; bool my_val = false;
    if (tid < rowcnt){ my_val = true; my_row = rowstart + tid; my_bo = b_out[my_row]; }

    // wait for all hp writers (per-wave subsets)
    for(;;){
      const u32 dv = aloadu32(&done[tid]);
      if (__all(dv == MAGIC)) break;
    }
    __syncthreads();

    const u32* cp2 = &cnt2[(cb&7)*32];
    for (int t=0;t<TMAX;t++){
      const u32 g = (u32)(t+1);
      // prefetch hp row t (plain, first-touch) before the wait
      float h8[8];
      LOAD8(h8, hp + (size_t)t*JOINT + 8*lane);
      if (tid==0){ while (aloadu32(cp2) < 32u*g) {} }
      __syncthreads();
      // direct per-lane u(g) gather (L1-bypassing) + z = tanh(h+u)
      float z8[8];
      {
        const u64* ub = (const u64*)(ws + WS_U + (size_t)(g&1)*2048);
        #pragma unroll
        for (int i=0;i<4;i++){
          const u64 v = aloadu64(&ub[4*lane + i]);
          z8[2*i]   = tanhf(h8[2*i]   + __uint_as_float((u32)v));
          z8[2*i+1] = tanhf(h8[2*i+1] + __uint_as_float((u32)(v>>32)));
        }
      }
      #pragma unroll
      for (int q=0;q<12;q++){
        float a=0.f;
        #pragma unroll
        for (int k=0;k<8;k++) a = fmaf(wout[q][k], z8[k], a);
        PL[(12*w+q)*68 + lane] = a;
      }
      __syncthreads();
      u64 key = 0; float lg = 0.f;
      if (tid < 48){
        const float* row = &PL[tid*68];
        float s = my_bo;
        #pragma unroll
        for (int k4=0;k4<16;k4++){
          const float4 v4 = *(const float4*)&row[4*k4];
          s += v4.x + v4.y + v4.z + v4.w;
        }
        lg = s;
        if (my_val) key = ((u64)ordbits(lg)<<16) | (u64)(0xFFFFu & ~(u32)my_row);
      }
      if (w == 0){
        const u64 bk = wredmax64(key);
        const float mw = unordbits((u32)(bk>>16));
        const float e  = my_val ? __expf(lg - mw) : 0.f;
        const float sw = wredsum(e);
        if (lane == 0){
          astoreu64(&saall[(g&3)*224 + cb], ((u64)g<<32) | (u64)__float_as_uint(sw));
          astoreu64(&pkall[(g&3)*224 + cb], ((u64)g<<48) | bk);
        }
      }
      __syncthreads();   // PL reuse fence
    }
  }
  // ============================ role: AGGREGATOR =============================
  else {
    float score = 0.0f;
    for (int t=0;t<TMAX;t++){
      const u32 g = (u32)(t+1);
      const u64* pks = pkall + (g&3)*224;
      const u64* sas = saall + (g&3)*224;
      u64 pk=0, sa=0;
      for(;;){
        if (tid < N_CONS){ pk = aloadu64(&pks[tid]); sa = aloadu64(&sas[tid]); }
        const int ok = (tid < N_CONS) ? (((u32)(pk>>48) >= g) & ((u32)(sa>>32) >= g)) : 1;
        if (__all(ok)) break;
      }
      { u64 m = wredmax64(pk); if (lane==0) R64[w]=m; }
      __syncthreads();
      u64 best = R64[0];
      #pragma unroll
      for (int i=1;i<4;i++){ const u64 x=R64[i]; best = (x>best)?x:best; }
      const float mstar = unordbits((u32)(best>>16));
      float term = (tid < N_CONS) ?
        __uint_as_float((u32)sa) * __expf(unordbits((u32)(pk>>16)) - mstar) : 0.f;
      term = wredsum(term);
      if (lane==0) RF[w] = term;
      __syncthreads();
      if (tid==0){
        const float S = RF[0]+RF[1]+RF[2]+RF[3];
        const int pred = (int)((~(u32)best) & 0xFFFFu);
        if (pred != 0) score += -logf(S);
        out[t] = (float)pred;
      }
      __syncthreads();   // protect R64/RF for next iteration
    }
    if (tid==0) out[TMAX] = score;
  }
}

extern "C" void kernel_launch(void* const* d_in, const int* in_sizes, int n_in,
                              void* d_out, int out_size, void* d_ws, size_t ws_size,
                              hipStream_t stream)
{
  const float* h     = (const float*)d_in[0];
  const float* embed = (const float*)d_in[1];
  const float* W_ih  = (const float*)d_in[2];
  const float* W_hh  = (const float*)d_in[3];
  const float* b_ih  = (const float*)d_in[4];
  const float* b_hh  = (const float*)d_in[5];
  const float* W_enc = (const float*)d_in[6];
  const float* b_enc = (const float*)d_in[7];
  const float* W_dec = (const float*)d_in[8];
  const float* W_out = (const float*)d_in[9];
  const float* b_out = (const float*)d_in[10];
  float* out = (float*)d_out;
  char* ws = (char*)d_ws;

  hipLaunchKernelGGL(rnnt_init, dim3(1), dim3(NT), 0, stream, ws);
  hipLaunchKernelGGL(rnnt_decode, dim3(NB), dim3(NT), 0, stream,
                     h, embed, W_ih, W_hh, b_ih, b_hh, W_enc, b_enc, W_dec, W_out, b_out,
                     out, ws);
}

// Round 3
// 20144.359 us; speedup vs baseline: 1.0616x; 1.0616x over previous
//
#include <hip/hip_runtime.h>
#include <stdint.h>

typedef unsigned long long u64;
typedef uint32_t u32;

#define NB     256
#define NT     256
#define TMAX   2048
#define EPROJS 1024
#define DUNITS 512
#define EMBED  512
#define JOINT  512
#define ODIM   10000

#define N_LSTM 32          // blocks 0..31: LSTM + fused partial-u producers
#define CONS0  32          // blocks 32..254: consumers (W_out)
#define N_CONS 223
#define AGG_B  255         // block 255: score/token aggregator
#define MAGIC  0xD07ED07Eu

// workspace layout (bytes); first 16 KB zeroed by rnnt_init
#define WS_PK   0          // u64[4][224]     consumer packs, 4-deep ring (7168)
#define WS_SA   7168       // u64[4][224]     consumer sum-exp, 4-deep ring
#define WS_DN   14336      // u32[256]        setup-done flags
#define WS_CNT  15360      // u32 epoch counter replicas [8] @ 128B stride
#define WS_Y    16384      // float[2][512]   y state, parity-buffered
#define WS_PART 20480      // u64[2][32][256] partial-u vectors (2 floats/u64), 128KB
#define WS_HP   163840     // float[2048][512] h_proj  (4 MB)

__device__ __forceinline__ float aloadf(const float* p){
  return __hip_atomic_load(p, __ATOMIC_RELAXED, __HIP_MEMORY_SCOPE_AGENT);
}
__device__ __forceinline__ void astoref(float* p, float v){
  __hip_atomic_store(p, v, __ATOMIC_RELAXED, __HIP_MEMORY_SCOPE_AGENT);
}
__device__ __forceinline__ u64 aloadu64(const u64* p){
  return __hip_atomic_load(p, __ATOMIC_RELAXED, __HIP_MEMORY_SCOPE_AGENT);
}
__device__ __forceinline__ void astoreu64(u64* p, u64 v){
  __hip_atomic_store(p, v, __ATOMIC_RELAXED, __HIP_MEMORY_SCOPE_AGENT);
}
__device__ __forceinline__ u32 aloadu32(const u32* p){
  return __hip_atomic_load(p, __ATOMIC_RELAXED, __HIP_MEMORY_SCOPE_AGENT);
}
__device__ __forceinline__ void astoreu32(u32* p, u32 v){
  __hip_atomic_store(p, v, __ATOMIC_RELAXED, __HIP_MEMORY_SCOPE_AGENT);
}

__device__ __forceinline__ u32 ordbits(float f){
  u32 u = __float_as_uint(f);
  return (u & 0x80000000u) ? ~u : (u | 0x80000000u);
}
__device__ __forceinline__ float unordbits(u32 o){
  u32 u = (o & 0x80000000u) ? (o & 0x7fffffffu) : ~o;
  return __uint_as_float(u);
}
__device__ __forceinline__ float sigmoidf_(float x){ return 1.0f/(1.0f+expf(-x)); }

__device__ __forceinline__ float wredsum(float v){
  #pragma unroll
  for (int o=32;o>0;o>>=1) v += __shfl_xor(v, o);
  return v;
}
__device__ __forceinline__ u64 wredmax64(u64 v){
  #pragma unroll
  for (int o=32;o>0;o>>=1){ u64 x = __shfl_xor(v, o); v = (x>v)?x:v; }
  return v;
}

#define LOAD8(dst, baseptr) { const float4* _p=(const float4*)(baseptr); \
  float4 _a=_p[0], _b=_p[1]; \
  dst[0]=_a.x; dst[1]=_a.y; dst[2]=_a.z; dst[3]=_a.w; \
  dst[4]=_b.x; dst[5]=_b.y; dst[6]=_b.z; dst[7]=_b.w; }

__global__ void rnnt_init(char* ws){
  // zero the 16 KB control region (rings, flags, counters)
  u32* p = (u32*)ws;
  for (int i = threadIdx.x; i < 4096; i += blockDim.x) p[i] = 0u;
}

__global__ void __launch_bounds__(NT, 1)
rnnt_decode(const float* __restrict__ h,    const float* __restrict__ embed,
            const float* __restrict__ W_ih, const float* __restrict__ W_hh,
            const float* __restrict__ b_ih, const float* __restrict__ b_hh,
            const float* __restrict__ W_enc,const float* __restrict__ b_enc,
            const float* __restrict__ W_dec,const float* __restrict__ W_out,
            const float* __restrict__ b_out,
            float* __restrict__ out, char* __restrict__ ws)
{
  const int b    = blockIdx.x;
  const int tid  = threadIdx.x;
  const int lane = tid & 63;
  const int w    = tid >> 6;

  float* ybuf = (float*)(ws + WS_Y);
  u64*  pkall = (u64*)(ws + WS_PK);
  u64*  saall = (u64*)(ws + WS_SA);
  u32*  done  = (u32*)(ws + WS_DN);
  u32*  cnt   = (u32*)(ws + WS_CNT);
  float* hp   = (float*)(ws + WS_HP);

  __shared__ float smem[8192];                 // 32 KB, multi-purpose
  float* PL = smem;                            // [64][68] partial sums
  float* GL = &smem[4416];                     // gates   (64)
  u64*   R64= (u64*)&smem[4480];               // 4 u64 reduce slots
  float* RF = &smem[4488];                     // 4 float reduce slots
  float* YO = &smem[4492];                     // fresh own-y (16)
  float* ZL = &smem[4544];                     // z, swizzled (512)

  // ================= setup: hp = h @ W_enc^T + b_enc (rows 8b..8b+7) =========
  {
    float (*lds_h)[EPROJS] = (float(*)[EPROJS])smem;
    #pragma unroll
    for (int r=0;r<8;r++){
      const float4 hv = *(const float4*)(h + (size_t)(8*b + r)*EPROJS + tid*4);
      *(float4*)&lds_h[r][tid*4] = hv;
    }
    __syncthreads();
    for (int p=0;p<2;p++){
      const int j = p*NT + tid;
      float acc[8] = {0,0,0,0,0,0,0,0};
      const float4* wrow = (const float4*)(W_enc + (size_t)j*EPROJS);
      for (int k4=0;k4<EPROJS/4;k4++){
        const float4 wv = wrow[k4];
        #pragma unroll
        for (int t8=0;t8<8;t8++){
          const float4 hv = *(const float4*)&lds_h[t8][k4*4];
          acc[t8] = fmaf(wv.x,hv.x, fmaf(wv.y,hv.y, fmaf(wv.z,hv.z, fmaf(wv.w,hv.w, acc[t8]))));
        }
      }
      const float be = b_enc[j];
      #pragma unroll
      for (int t8=0;t8<8;t8++)
        astoref(&hp[(size_t)(8*b+t8)*JOINT + j], acc[t8] + be);
    }
    asm volatile("s_waitcnt vmcnt(0)" ::: "memory");
    if (tid==0) astoreu32(&done[b], MAGIC);
    __syncthreads();   // smem reuse fence
  }

  // ============================ role: LSTM + fused partial-u =================
  if (b < N_LSTM){
    const int d = b;
    float wih[16][8], whh[16][8];
    #pragma unroll
    for (int q=0;q<16;q++){
      const int gr = w*DUNITS + 16*d + q;       // wave w = gate type (i,f,g,o)
      LOAD8(wih[q], W_ih + (size_t)gr*EMBED  + lane*8);
      LOAD8(whh[q], W_hh + (size_t)gr*DUNITS + lane*8);
    }
    // W_dec COLUMN slice: thread owns rows 2tid,2tid+1 x cols [16d,16d+16)
    float wdc0[16], wdc1[16];
    {
      const float4* p0 = (const float4*)(W_dec + (size_t)(2*tid)*DUNITS   + 16*d);
      const float4* p1 = (const float4*)(W_dec + (size_t)(2*tid+1)*DUNITS + 16*d);
      #pragma unroll
      for (int k4=0;k4<4;k4++){
        const float4 a = p0[k4];
        wdc0[4*k4+0]=a.x; wdc0[4*k4+1]=a.y; wdc0[4*k4+2]=a.z; wdc0[4*k4+3]=a.w;
        const float4 c = p1[k4];
        wdc1[4*k4+0]=c.x; wdc1[4*k4+1]=c.y; wdc1[4*k4+2]=c.z; wdc1[4*k4+3]=c.w;
      }
    }
    float bias_r = 0.0f;
    if (tid < 64){
      const int gr = (tid>>4)*DUNITS + 16*d + (tid&15);
      bias_r = b_ih[gr] + b_hh[gr];
    }
    // bootstrap: y(1) + partial(1), then bump cnt
    float c_st = 0.0f, y_st = 0.0f;
    if (tid < 16){
      const int j = 16*d + tid;
      const float gi = b_ih[j]            + b_hh[j];
      const float gg = b_ih[2*DUNITS + j] + b_hh[2*DUNITS + j];
      const float go = b_ih[3*DUNITS + j] + b_hh[3*DUNITS + j];
      c_st = sigmoidf_(gi)*tanhf(gg);
      y_st = sigmoidf_(go)*tanhf(c_st);
      YO[tid] = y_st;
      astoref(&ybuf[512 + j], y_st);
    }
    __syncthreads();
    {
      float p0=0.f, p1=0.f;
      #pragma unroll
      for (int k=0;k<16;k++){ p0 = fmaf(wdc0[k], YO[k], p0); p1 = fmaf(wdc1[k], YO[k], p1); }
      u64* up = (u64*)(ws + WS_PART + 65536 + (size_t)d*2048);
      astoreu64(&up[tid], ((u64)__float_as_uint(p1)<<32) | (u64)__float_as_uint(p0));
    }
    asm volatile("s_waitcnt vmcnt(0)" ::: "memory");
    __syncthreads();
    if (tid < 8) atomicAdd(&cnt[tid*32], 1u);

    const u32* myrep = &cnt[(((u32)(4*d+w))&7)*32];
    for (int t=0;t<TMAX;t++){
      const u32 g = (u32)(t+1);
      // --- per-wave spin: y(g)+part(g) complete ---
      while (aloadu32(myrep) < 32u*g) {}
      // --- direct per-lane y(g) gather ---
      float y8[8];
      {
        const u64* yb = (const u64*)(ws + WS_Y + (size_t)(g&1)*2048);
        #pragma unroll
        for (int i=0;i<4;i++){
          const u64 v = aloadu64(&yb[4*lane + i]);
          y8[2*i]   = __uint_as_float((u32)v);
          y8[2*i+1] = __uint_as_float((u32)(v>>32));
        }
      }
      // --- vp = W_hh @ y partials (hidden under pack wait) ---
      float vp[16];
      #pragma unroll
      for (int q=0;q<16;q++){
        float a=0.f;
        #pragma unroll
        for (int k=0;k<8;k++) a = fmaf(whh[q][k], y8[k], a);
        vp[q] = a;
      }
      // --- poll packs(g), per-wave subsets, tag-embedded ---
      u64 pk = 0;
      {
        const u64* pks = pkall + (g&3)*224;
        for(;;){
          pk = (tid < N_CONS) ? aloadu64(&pks[tid]) : 0;
          const int ok = (tid < N_CONS) ? ((u32)(pk>>48) >= g) : 1;
          if (__all(ok)) break;
        }
      }
      const u64 m = wredmax64(pk);
      if (lane==0) R64[w] = m;
      // speculative embed prefetch of this wave's candidate
      const int predw = (int)((~(u32)m) & 0xFFFFu);
      float e8[8];
      LOAD8(e8, embed + (size_t)predw*EMBED + 8*lane);
      __syncthreads();
      u64 best = R64[0];
      #pragma unroll
      for (int i=1;i<4;i++){ const u64 x=R64[i]; best = (x>best)?x:best; }
      const int pred = (int)((~(u32)best) & 0xFFFFu);
      const int emitted = (pred != 0);
      if (m != best){                            // wave-uniform mispredict: L1-hot reload
        LOAD8(e8, embed + (size_t)pred*EMBED + 8*lane);
      }
      #pragma unroll
      for (int q=0;q<16;q++){
        float a = vp[q];
        #pragma unroll
        for (int k=0;k<8;k++) a = fmaf(wih[q][k], e8[k], a);
        PL[(w*16+q)*68 + lane] = a;
      }
      __syncthreads();
      if (tid < 64){
        const float* row = &PL[tid*68];
        float s = bias_r;
        #pragma unroll
        for (int k4=0;k4<16;k4++){
          const float4 v4 = *(const float4*)&row[4*k4];
          s += v4.x + v4.y + v4.z + v4.w;
        }
        GL[tid] = s;
      }
      __syncthreads();
      if (tid < 16){
        const float gi=GL[tid], gf=GL[16+tid], gg=GL[32+tid], go=GL[48+tid];
        const float cn = sigmoidf_(gf)*c_st + sigmoidf_(gi)*tanhf(gg);
        const float yn = sigmoidf_(go)*tanhf(cn);
        if (emitted){ c_st = cn; y_st = yn; }
        YO[tid] = y_st;
        if (t < TMAX-1) astoref(&ybuf[((g+1)&1)*512 + 16*d + tid], y_st);
      }
      __syncthreads();                           // YO visible to all waves
      if (t < TMAX-1){
        float p0=0.f, p1=0.f;
        #pragma unroll
        for (int k=0;k<16;k++){ p0 = fmaf(wdc0[k], YO[k], p0); p1 = fmaf(wdc1[k], YO[k], p1); }
        u64* up = (u64*)(ws + WS_PART + (size_t)((g+1)&1)*65536 + (size_t)d*2048);
        astoreu64(&up[tid], ((u64)__float_as_uint(p1)<<32) | (u64)__float_as_uint(p0));
      }
      asm volatile("s_waitcnt vmcnt(0)" ::: "memory");
      __syncthreads();                           // all waves' stores drained
      if (t < TMAX-1 && tid < 8) atomicAdd(&cnt[tid*32], 1u);
    }
  }
  // ============================ role: CONSUMER ===============================
  else if (b < AGG_B){
    const int cb = b - CONS0;
    int rowstart, rowcnt;
    if (cb < 188){ rowstart = cb*45;                 rowcnt = 45; }
    else         { rowstart = 8460 + (cb-188)*44;    rowcnt = 44; }
    float wout[12][8];
    #pragma unroll
    for (int q=0;q<12;q++){
      const int s = 12*w + q;
      if (s < rowcnt){
        LOAD8(wout[q], W_out + (size_t)(rowstart+s)*JOINT + lane*8);
      } else {
        #pragma unroll
        for (int k=0;k<8;k++) wout[q][k]=0.f;
      }
    }
    float my_bo = 0.f; int my_row = 0; bool my_val = false;
    if (tid < rowcnt){ my_val = true; my_row = rowstart + tid; my_bo = b_out[my_row]; }

    // wait for all hp writers (per-wave quarters; barrier completes coverage)
    for(;;){
      const u32 dv = aloadu32(&done[tid]);
      if (__all(dv == MAGIC)) break;
    }
    __syncthreads();

    const u32* myrep = &cnt[(((u32)(4*cb+w))&7)*32];
    for (int t=0;t<TMAX;t++){
      const u32 g = (u32)(t+1);
      // prefetch hp pair for this thread's elements before the wait
      const float2 h2 = *(const float2*)(hp + (size_t)t*JOINT + 2*tid);
      // --- per-wave spin on epoch counter ---
      while (aloadu32(myrep) < 32u*g) {}
      // --- gather 32 partials for elements 2tid,2tid+1, sum ---
      float u0 = 0.f, u1 = 0.f;
      {
        const u64* pb = (const u64*)(ws + WS_PART + (size_t)(g&1)*65536);
        u64 v[32];
        #pragma unroll
        for (int p=0;p<32;p++) v[p] = aloadu64(&pb[p*256 + tid]);
        #pragma unroll
        for (int p=0;p<32;p++){
          u0 += __uint_as_float((u32)v[p]);
          u1 += __uint_as_float((u32)(v[p]>>32));
        }
      }
      // z = tanh(h+u), staged swizzled: s(j)=(j&7)*64+(j>>3)
      {
        const int j0 = 2*tid, j1 = 2*tid+1;
        ZL[(j0&7)*64 + (j0>>3)] = tanhf(h2.x + u0);
        ZL[(j1&7)*64 + (j1>>3)] = tanhf(h2.y + u1);
      }
      __syncthreads();
      float z8[8];
      #pragma unroll
      for (int e=0;e<8;e++) z8[e] = ZL[e*64 + lane];   // z[8*lane+e], conflict-free
      #pragma unroll
      for (int q=0;q<12;q++){
        float a=0.f;
        #pragma unroll
        for (int k=0;k<8;k++) a = fmaf(wout[q][k], z8[k], a);
        PL[(12*w+q)*68 + lane] = a;
      }
      __syncthreads();
      u64 key = 0; float lg = 0.f;
      if (tid < 48){
        const float* row = &PL[tid*68];
        float s = my_bo;
        #pragma unroll
        for (int k4=0;k4<16;k4++){
          const float4 v4 = *(const float4*)&row[4*k4];
          s += v4.x + v4.y + v4.z + v4.w;
        }
        lg = s;
        if (my_val) key = ((u64)ordbits(lg)<<16) | (u64)(0xFFFFu & ~(u32)my_row);
      }
      if (w == 0){
        const u64 bk = wredmax64(key);
        const float mw = unordbits((u32)(bk>>16));
        const float e  = my_val ? __expf(lg - mw) : 0.f;
        const float sw = wredsum(e);
        if (lane == 0){
          astoreu64(&saall[(g&3)*224 + cb], ((u64)g<<32) | (u64)__float_as_uint(sw));
          astoreu64(&pkall[(g&3)*224 + cb], ((u64)g<<48) | bk);
        }
      }
      __syncthreads();   // PL/ZL reuse fence
    }
  }
  // ============================ role: AGGREGATOR =============================
  else {
    float score = 0.0f;
    for (int t=0;t<TMAX;t++){
      const u32 g = (u32)(t+1);
      const u64* pks = pkall + (g&3)*224;
      const u64* sas = saall + (g&3)*224;
      u64 pk=0, sa=0;
      for(;;){
        if (tid < N_CONS){ pk = aloadu64(&pks[tid]); sa = aloadu64(&sas[tid]); }
        const int ok = (tid < N_CONS) ? (((u32)(pk>>48) >= g) & ((u32)(sa>>32) >= g)) : 1;
        if (__all(ok)) break;
      }
      { u64 m = wredmax64(pk); if (lane==0) R64[w]=m; }
      __syncthreads();
      u64 best = R64[0];
      #pragma unroll
      for (int i=1;i<4;i++){ const u64 x=R64[i]; best = (x>best)?x:best; }
      const float mstar = unordbits((u32)(best>>16));
      float term = (tid < N_CONS) ?
        __uint_as_float((u32)sa) * __expf(unordbits((u32)(pk>>16)) - mstar) : 0.f;
      term = wredsum(term);
      if (lane==0) RF[w] = term;
      __syncthreads();
      if (tid==0){
        const float S = RF[0]+RF[1]+RF[2]+RF[3];
        const int pred = (int)((~(u32)best) & 0xFFFFu);
        if (pred != 0) score += -logf(S);
        out[t] = (float)pred;
      }
      __syncthreads();   // protect R64/RF for next iteration
    }
    if (tid==0) out[TMAX] = score;
  }
}

extern "C" void kernel_launch(void* const* d_in, const int* in_sizes, int n_in,
                              void* d_out, int out_size, void* d_ws, size_t ws_size,
                              hipStream_t stream)
{
  const float* h     = (const float*)d_in[0];
  const float* embed = (const float*)d_in[1];
  const float* W_ih  = (const float*)d_in[2];
  const float* W_hh  = (const float*)d_in[3];
  const float* b_ih  = (const float*)d_in[4];
  const float* b_hh  = (const float*)d_in[5];
  const float* W_enc = (const float*)d_in[6];
  const float* b_enc = (const float*)d_in[7];
  const float* W_dec = (const float*)d_in[8];
  const float* W_out = (const float*)d_in[9];
  const float* b_out = (const float*)d_in[10];
  float* out = (float*)d_out;
  char* ws = (char*)d_ws;

  hipLaunchKernelGGL(rnnt_init, dim3(1), dim3(NT), 0, stream, ws);
  hipLaunchKernelGGL(rnnt_decode, dim3(NB), dim3(NT), 0, stream,
                     h, embed, W_ih, W_hh, b_ih, b_hh, W_enc, b_enc, W_dec, W_out, b_out,
                     out, ws);
}

// Round 4
// 19727.133 us; speedup vs baseline: 1.0841x; 1.0211x over previous
//
#include <hip/hip_runtime.h>
#include <stdint.h>

typedef unsigned long long u64;
typedef uint32_t u32;

#define NB     256
#define NT     256
#define TMAX   2048
#define EPROJS 1024
#define DUNITS 512
#define EMBED  512
#define JOINT  512
#define ODIM   10000

#define N_LSTM 32          // blocks 0..31: LSTM + row-partitioned tagged-u producers
#define CONS0  32          // blocks 32..254: consumers (W_out)
#define N_CONS 223
#define AGG_B  255         // block 255: score/token aggregator
#define MAGIC  0xD07ED07Eu

// workspace layout (bytes); first 32 KB zeroed by rnnt_init
#define WS_PK   0          // u64[4][224]   consumer packs, 4-deep ring (tag in bits 48+)
#define WS_SA   7168       // u64[4][224]   consumer sum-exp, 4-deep ring (tag in bits 32+)
#define WS_DN   14336      // u32[256]      setup-done flags
#define WS_Y    15360      // u64[2][512]   tagged y words (epoch<<32 | f32), parity-2
#define WS_U    23552      // u64[2][512]   tagged u words, parity-2
#define WS_HP   32768      // float[2048][512] h_proj  (4 MB)

__device__ __forceinline__ float aloadf(const float* p){
  return __hip_atomic_load(p, __ATOMIC_RELAXED, __HIP_MEMORY_SCOPE_AGENT);
}
__device__ __forceinline__ void astoref(float* p, float v){
  __hip_atomic_store(p, v, __ATOMIC_RELAXED, __HIP_MEMORY_SCOPE_AGENT);
}
__device__ __forceinline__ u64 aloadu64(const u64* p){
  return __hip_atomic_load(p, __ATOMIC_RELAXED, __HIP_MEMORY_SCOPE_AGENT);
}
__device__ __forceinline__ void astoreu64(u64* p, u64 v){
  __hip_atomic_store(p, v, __ATOMIC_RELAXED, __HIP_MEMORY_SCOPE_AGENT);
}
__device__ __forceinline__ u32 aloadu32(const u32* p){
  return __hip_atomic_load(p, __ATOMIC_RELAXED, __HIP_MEMORY_SCOPE_AGENT);
}
__device__ __forceinline__ void astoreu32(u32* p, u32 v){
  __hip_atomic_store(p, v, __ATOMIC_RELAXED, __HIP_MEMORY_SCOPE_AGENT);
}

__device__ __forceinline__ u32 ordbits(float f){
  u32 u = __float_as_uint(f);
  return (u & 0x80000000u) ? ~u : (u | 0x80000000u);
}
__device__ __forceinline__ float unordbits(u32 o){
  u32 u = (o & 0x80000000u) ? (o & 0x7fffffffu) : ~o;
  return __uint_as_float(u);
}
__device__ __forceinline__ float sigmoidf_(float x){ return 1.0f/(1.0f+expf(-x)); }

__device__ __forceinline__ float wredsum(float v){
  #pragma unroll
  for (int o=32;o>0;o>>=1) v += __shfl_xor(v, o);
  return v;
}
__device__ __forceinline__ u64 wredmax64(u64 v){
  #pragma unroll
  for (int o=32;o>0;o>>=1){ u64 x = __shfl_xor(v, o); v = (x>v)?x:v; }
  return v;
}

// ZL swizzle: j = 8*lane + e  ->  slot (j&7)*64 + ((j>>3) ^ ((j&7)<<2))
// write: <=2-way bank alias; read z8[e]: lane^const -> conflict-free.
__device__ __forceinline__ int zslot(int j){
  return (j&7)*64 + ((j>>3) ^ ((j&7)<<2));
}

#define LOAD8(dst, baseptr) { const float4* _p=(const float4*)(baseptr); \
  float4 _a=_p[0], _b=_p[1]; \
  dst[0]=_a.x; dst[1]=_a.y; dst[2]=_a.z; dst[3]=_a.w; \
  dst[4]=_b.x; dst[5]=_b.y; dst[6]=_b.z; dst[7]=_b.w; }

__global__ void rnnt_init(char* ws){
  // zero the 32 KB control region (rings, flags, tagged y/u)
  u32* p = (u32*)ws;
  for (int i = threadIdx.x; i < 8192; i += blockDim.x) p[i] = 0u;
}

__global__ void __launch_bounds__(NT, 1)
rnnt_decode(const float* __restrict__ h,    const float* __restrict__ embed,
            const float* __restrict__ W_ih, const float* __restrict__ W_hh,
            const float* __restrict__ b_ih, const float* __restrict__ b_hh,
            const float* __restrict__ W_enc,const float* __restrict__ b_enc,
            const float* __restrict__ W_dec,const float* __restrict__ W_out,
            const float* __restrict__ b_out,
            float* __restrict__ out, char* __restrict__ ws)
{
  const int b    = blockIdx.x;
  const int tid  = threadIdx.x;
  const int lane = tid & 63;
  const int w    = tid >> 6;

  u64*  ytag  = (u64*)(ws + WS_Y);
  u64*  utag  = (u64*)(ws + WS_U);
  u64*  pkall = (u64*)(ws + WS_PK);
  u64*  saall = (u64*)(ws + WS_SA);
  u32*  done  = (u32*)(ws + WS_DN);
  float* hp   = (float*)(ws + WS_HP);

  __shared__ float smem[8192];                 // 32 KB, multi-purpose
  float* PL = smem;                            // [64][68] partial sums
  float* GL = &smem[4416];                     // gates   (64)
  u64*   R64= (u64*)&smem[4480];               // 4 u64 reduce slots
  float* RF = &smem[4488];                     // 4 float reduce slots
  float* ZL = &smem[4544];                     // z, swizzled (512)

  // ================= setup: hp = h @ W_enc^T + b_enc (rows 8b..8b+7) =========
  {
    float (*lds_h)[EPROJS] = (float(*)[EPROJS])smem;
    #pragma unroll
    for (int r=0;r<8;r++){
      const float4 hv = *(const float4*)(h + (size_t)(8*b + r)*EPROJS + tid*4);
      *(float4*)&lds_h[r][tid*4] = hv;
    }
    __syncthreads();
    for (int p=0;p<2;p++){
      const int j = p*NT + tid;
      float acc[8] = {0,0,0,0,0,0,0,0};
      const float4* wrow = (const float4*)(W_enc + (size_t)j*EPROJS);
      for (int k4=0;k4<EPROJS/4;k4++){
        const float4 wv = wrow[k4];
        #pragma unroll
        for (int t8=0;t8<8;t8++){
          const float4 hv = *(const float4*)&lds_h[t8][k4*4];
          acc[t8] = fmaf(wv.x,hv.x, fmaf(wv.y,hv.y, fmaf(wv.z,hv.z, fmaf(wv.w,hv.w, acc[t8]))));
        }
      }
      const float be = b_enc[j];
      #pragma unroll
      for (int t8=0;t8<8;t8++)
        astoref(&hp[(size_t)(8*b+t8)*JOINT + j], acc[t8] + be);
    }
    asm volatile("s_waitcnt vmcnt(0)" ::: "memory");
    if (tid==0) astoreu32(&done[b], MAGIC);
    __syncthreads();   // smem reuse fence
  }

  // ============================ role: LSTM + tagged-u rows ===================
  if (b < N_LSTM){
    const int d = b;
    float wih[16][8], whh[16][8];
    #pragma unroll
    for (int q=0;q<16;q++){
      const int gr = w*DUNITS + 16*d + q;       // wave w = gate type (i,f,g,o)
      LOAD8(wih[q], W_ih + (size_t)gr*EMBED  + lane*8);
      LOAD8(whh[q], W_hh + (size_t)gr*DUNITS + lane*8);
    }
    // W_dec ROW slice: wave w owns rows 16d+4w .. 16d+4w+3 (full 512-wide)
    float wdr[4][8];
    #pragma unroll
    for (int i=0;i<4;i++){
      const int r = 16*d + 4*w + i;
      LOAD8(wdr[i], W_dec + (size_t)r*DUNITS + 8*lane);
    }
    float bias_r = 0.0f;
    if (tid < 64){
      const int gr = (tid>>4)*DUNITS + 16*d + (tid&15);
      bias_r = b_ih[gr] + b_hh[gr];
    }
    // bootstrap: publish tagged y(1) (parity 1), fire-and-forget
    float c_st = 0.0f, y_st = 0.0f;
    if (tid < 16){
      const int j = 16*d + tid;
      const float gi = b_ih[j]            + b_hh[j];
      const float gg = b_ih[2*DUNITS + j] + b_hh[2*DUNITS + j];
      const float go = b_ih[3*DUNITS + j] + b_hh[3*DUNITS + j];
      c_st = sigmoidf_(gi)*tanhf(gg);
      y_st = sigmoidf_(go)*tanhf(c_st);
      astoreu64(&ytag[512 + j], ((u64)1u<<32) | (u64)__float_as_uint(y_st));
    }

    for (int t=0;t<TMAX;t++){
      const u32 g = (u32)(t+1);
      // --- per-lane poll y(g): payload-carrying tagged words ---
      const u64* yb = ytag + (size_t)(g&1)*512;
      u64 yv[8];
      for(;;){
        bool ok = true;
        #pragma unroll
        for (int i=0;i<8;i++){
          yv[i] = aloadu64(&yb[8*lane + i]);
          ok &= ((u32)(yv[i]>>32) == g);
        }
        if (ok) break;
      }
      float y8[8];
      #pragma unroll
      for (int i=0;i<8;i++) y8[i] = __uint_as_float((u32)yv[i]);
      // --- u rows (16d+4w+i) = W_dec rows @ y; publish ASAP, fire-and-forget --
      {
        float p0=0.f,p1=0.f,p2=0.f,p3=0.f;
        #pragma unroll
        for (int k=0;k<8;k++){
          p0 = fmaf(wdr[0][k], y8[k], p0);
          p1 = fmaf(wdr[1][k], y8[k], p1);
          p2 = fmaf(wdr[2][k], y8[k], p2);
          p3 = fmaf(wdr[3][k], y8[k], p3);
        }
        #pragma unroll
        for (int o=32;o>0;o>>=1){
          p0 += __shfl_xor(p0,o); p1 += __shfl_xor(p1,o);
          p2 += __shfl_xor(p2,o); p3 += __shfl_xor(p3,o);
        }
        if (lane < 4){
          const float pv = (lane==0)?p0:(lane==1)?p1:(lane==2)?p2:p3;
          astoreu64(&utag[(size_t)(g&1)*512 + 16*d + 4*w + lane],
                    ((u64)g<<32) | (u64)__float_as_uint(pv));
        }
      }
      // --- vp = W_hh @ y partials (hidden under consumer latency) ---
      float vp[16];
      #pragma unroll
      for (int q=0;q<16;q++){
        float a=0.f;
        #pragma unroll
        for (int k=0;k<8;k++) a = fmaf(whh[q][k], y8[k], a);
        vp[q] = a;
      }
      // --- poll packs(g), per-wave subsets, tag-embedded ---
      u64 pk = 0;
      {
        const u64* pks = pkall + (g&3)*224;
        for(;;){
          pk = (tid < N_CONS) ? aloadu64(&pks[tid]) : 0;
          const int ok = (tid < N_CONS) ? ((u32)(pk>>48) >= g) : 1;
          if (__all(ok)) break;
        }
      }
      const u64 m = wredmax64(pk);
      if (lane==0) R64[w] = m;
      // speculative embed prefetch of this wave's candidate
      const int predw = (int)((~(u32)m) & 0xFFFFu);
      float e8[8];
      LOAD8(e8, embed + (size_t)predw*EMBED + 8*lane);
      __syncthreads();
      u64 best = R64[0];
      #pragma unroll
      for (int i=1;i<4;i++){ const u64 x=R64[i]; best = (x>best)?x:best; }
      const int pred = (int)((~(u32)best) & 0xFFFFu);
      const int emitted = (pred != 0);
      if (m != best){                            // wave-uniform mispredict: hot reload
        LOAD8(e8, embed + (size_t)pred*EMBED + 8*lane);
      }
      #pragma unroll
      for (int q=0;q<16;q++){
        float a = vp[q];
        #pragma unroll
        for (int k=0;k<8;k++) a = fmaf(wih[q][k], e8[k], a);
        PL[(w*16+q)*68 + lane] = a;
      }
      __syncthreads();
      if (tid < 64){
        const float* row = &PL[tid*68];
        float s = bias_r;
        #pragma unroll
        for (int k4=0;k4<16;k4++){
          const float4 v4 = *(const float4*)&row[4*k4];
          s += v4.x + v4.y + v4.z + v4.w;
        }
        GL[tid] = s;
      }
      __syncthreads();
      if (tid < 16){
        const float gi=GL[tid], gf=GL[16+tid], gg=GL[32+tid], go=GL[48+tid];
        const float cn = sigmoidf_(gf)*c_st + sigmoidf_(gi)*tanhf(gg);
        const float yn = sigmoidf_(go)*tanhf(cn);
        if (emitted){ c_st = cn; y_st = yn; }
        if (t < TMAX-1)
          astoreu64(&ytag[(size_t)((g+1)&1)*512 + 16*d + tid],
                    ((u64)(g+1)<<32) | (u64)__float_as_uint(y_st));
      }
      // no trailing barrier: next iteration's R64/PL writes are ordered by
      // the y/u/pack dependency cycle + the three barriers above.
    }
  }
  // ============================ role: CONSUMER ===============================
  else if (b < AGG_B){
    const int cb = b - CONS0;
    int rowstart, rowcnt;
    if (cb < 188){ rowstart = cb*45;                 rowcnt = 45; }
    else         { rowstart = 8460 + (cb-188)*44;    rowcnt = 44; }
    float wout[12][8];
    #pragma unroll
    for (int q=0;q<12;q++){
      const int s = 12*w + q;
      if (s < rowcnt){
        LOAD8(wout[q], W_out + (size_t)(rowstart+s)*JOINT + lane*8);
      } else {
        #pragma unroll
        for (int k=0;k<8;k++) wout[q][k]=0.f;
      }
    }
    float my_bo = 0.f; int my_row = 0; bool my_val = false;
    if (tid < rowcnt){ my_val = true; my_row = rowstart + tid; my_bo = b_out[my_row]; }

    // wait for all hp writers
    for(;;){
      const u32 dv = aloadu32(&done[tid]);
      if (__all(dv == MAGIC)) break;
    }
    __syncthreads();

    const int j0 = 2*tid, j1 = 2*tid+1;
    const int s0 = zslot(j0), s1 = zslot(j1);
    for (int t=0;t<TMAX;t++){
      const u32 g = (u32)(t+1);
      // prefetch hp pair (off critical path)
      const float2 h2 = *(const float2*)(hp + (size_t)t*JOINT + j0);
      // --- poll OWN two tagged u words: detect == payload, one 16B load path --
      const u64* ub = utag + (size_t)(g&1)*512;
      u64 ua, ub2;
      for(;;){
        ua  = aloadu64(&ub[j0]);
        ub2 = aloadu64(&ub[j1]);
        if ( (((u32)(ua>>32))==g) & (((u32)(ub2>>32))==g) ) break;
      }
      ZL[s0] = tanhf(h2.x + __uint_as_float((u32)ua));
      ZL[s1] = tanhf(h2.y + __uint_as_float((u32)ub2));
      __syncthreads();
      float z8[8];
      #pragma unroll
      for (int e=0;e<8;e++) z8[e] = ZL[e*64 + (lane ^ (e<<2))];   // z[8*lane+e]
      #pragma unroll
      for (int q=0;q<12;q++){
        float a=0.f;
        #pragma unroll
        for (int k=0;k<8;k++) a = fmaf(wout[q][k], z8[k], a);
        PL[(12*w+q)*68 + lane] = a;
      }
      __syncthreads();
      u64 key = 0; float lg = 0.f;
      if (tid < 48){
        const float* row = &PL[tid*68];
        float s = my_bo;
        #pragma unroll
        for (int k4=0;k4<16;k4++){
          const float4 v4 = *(const float4*)&row[4*k4];
          s += v4.x + v4.y + v4.z + v4.w;
        }
        lg = s;
        if (my_val) key = ((u64)ordbits(lg)<<16) | (u64)(0xFFFFu & ~(u32)my_row);
      }
      if (w == 0){
        const u64 bk = wredmax64(key);
        const float mw = unordbits((u32)(bk>>16));
        const float e  = my_val ? __expf(lg - mw) : 0.f;
        const float sw = wredsum(e);
        if (lane == 0){
          astoreu64(&saall[(g&3)*224 + cb], ((u64)g<<32) | (u64)__float_as_uint(sw));
          astoreu64(&pkall[(g&3)*224 + cb], ((u64)g<<48) | bk);
        }
      }
      // ZL(g+1)/PL(g+1) writes are gated by the u(g+1) poll, which requires
      // this block's pack(g) (wave 0) to have been published -> no extra barrier.
    }
  }
  // ============================ role: AGGREGATOR =============================
  else {
    float score = 0.0f;
    for (int t=0;t<TMAX;t++){
      const u32 g = (u32)(t+1);
      const u64* pks = pkall + (g&3)*224;
      const u64* sas = saall + (g&3)*224;
      u64 pk=0, sa=0;
      for(;;){
        if (tid < N_CONS){ pk = aloadu64(&pks[tid]); sa = aloadu64(&sas[tid]); }
        const int ok = (tid < N_CONS) ? (((u32)(pk>>48)==g) & (((u32)(sa>>32))==g)) : 1;
        if (__all(ok)) break;
      }
      { u64 m = wredmax64(pk); if (lane==0) R64[w]=m; }
      __syncthreads();
      u64 best = R64[0];
      #pragma unroll
      for (int i=1;i<4;i++){ const u64 x=R64[i]; best = (x>best)?x:best; }
      const float mstar = unordbits((u32)(best>>16));
      float term = (tid < N_CONS) ?
        __uint_as_float((u32)sa) * __expf(unordbits((u32)(pk>>16)) - mstar) : 0.f;
      term = wredsum(term);
      if (lane==0) RF[w] = term;
      __syncthreads();
      if (tid==0){
        const float S = RF[0]+RF[1]+RF[2]+RF[3];
        const int pred = (int)((~(u32)best) & 0xFFFFu);
        if (pred != 0) score += -logf(S);
        out[t] = (float)pred;
      }
      __syncthreads();   // protect R64/RF for next iteration
    }
    if (tid==0) out[TMAX] = score;
  }
}

extern "C" void kernel_launch(void* const* d_in, const int* in_sizes, int n_in,
                              void* d_out, int out_size, void* d_ws, size_t ws_size,
                              hipStream_t stream)
{
  const float* h     = (const float*)d_in[0];
  const float* embed = (const float*)d_in[1];
  const float* W_ih  = (const float*)d_in[2];
  const float* W_hh  = (const float*)d_in[3];
  const float* b_ih  = (const float*)d_in[4];
  const float* b_hh  = (const float*)d_in[5];
  const float* W_enc = (const float*)d_in[6];
  const float* b_enc = (const float*)d_in[7];
  const float* W_dec = (const float*)d_in[8];
  const float* W_out = (const float*)d_in[9];
  const float* b_out = (const float*)d_in[10];
  float* out = (float*)d_out;
  char* ws = (char*)d_ws;

  hipLaunchKernelGGL(rnnt_init, dim3(1), dim3(NT), 0, stream, ws);
  hipLaunchKernelGGL(rnnt_decode, dim3(NB), dim3(NT), 0, stream,
                     h, embed, W_ih, W_hh, b_ih, b_hh, W_enc, b_enc, W_dec, W_out, b_out,
                     out, ws);
}

// Round 6
// 17704.913 us; speedup vs baseline: 1.2079x; 1.1142x over previous
//
#include <hip/hip_runtime.h>
#include <stdint.h>

typedef unsigned long long u64;
typedef uint32_t u32;

#define NB     256
#define NT     256
#define TMAX   2048
#define EPROJS 1024
#define DUNITS 512
#define EMBED  512
#define JOINT  512
#define ODIM   10000

#define N_LSTM 32          // blocks 0..31: LSTM + fused partial-u + u-slice reduce
#define CONS0  32          // blocks 32..254: consumers (W_out)
#define N_CONS 223
#define AGG_B  255         // block 255: score/token aggregator
#define MAGIC  0xD07ED07Eu

// workspace layout (bytes); first 155648 B zeroed by rnnt_init
// total = 155648 + 4 MB = 4,349,952 B  (< r3-proven 4,358,144)
#define WS_PK   0          // u64[4][224]   consumer packs, 4-deep ring (tag bits 48+)
#define WS_SA   7168       // u64[4][224]   consumer sum-exp, 4-deep ring (tag bits 32+)
#define WS_DN   14336      // u32[256]      setup-done flags
#define WS_AGG  15360      // u32 aggregator-epoch replicas [8] @ 128B stride
#define WS_Y    16384      // u64[512]      tagged y words (epoch<<32 | f32), single buf
#define WS_U    20480      // u64[512]      tagged u words, single buf
#define WS_PART 24576      // u64[32][512]  tagged partial-u, single buf (128 KB)
#define WS_HP   155648     // float[2048][512] h_proj  (4 MB)

__device__ __forceinline__ float aloadf(const float* p){
  return __hip_atomic_load(p, __ATOMIC_RELAXED, __HIP_MEMORY_SCOPE_AGENT);
}
__device__ __forceinline__ void astoref(float* p, float v){
  __hip_atomic_store(p, v, __ATOMIC_RELAXED, __HIP_MEMORY_SCOPE_AGENT);
}
__device__ __forceinline__ u64 aloadu64(const u64* p){
  return __hip_atomic_load(p, __ATOMIC_RELAXED, __HIP_MEMORY_SCOPE_AGENT);
}
__device__ __forceinline__ void astoreu64(u64* p, u64 v){
  __hip_atomic_store(p, v, __ATOMIC_RELAXED, __HIP_MEMORY_SCOPE_AGENT);
}
__device__ __forceinline__ u32 aloadu32(const u32* p){
  return __hip_atomic_load(p, __ATOMIC_RELAXED, __HIP_MEMORY_SCOPE_AGENT);
}
__device__ __forceinline__ void astoreu32(u32* p, u32 v){
  __hip_atomic_store(p, v, __ATOMIC_RELAXED, __HIP_MEMORY_SCOPE_AGENT);
}

__device__ __forceinline__ u32 ordbits(float f){
  u32 u = __float_as_uint(f);
  return (u & 0x80000000u) ? ~u : (u | 0x80000000u);
}
__device__ __forceinline__ float unordbits(u32 o){
  u32 u = (o & 0x80000000u) ? (o & 0x7fffffffu) : ~o;
  return __uint_as_float(u);
}
__device__ __forceinline__ float sigmoidf_(float x){ return 1.0f/(1.0f+expf(-x)); }

__device__ __forceinline__ float wredsum(float v){
  #pragma unroll
  for (int o=32;o>0;o>>=1) v += __shfl_xor(v, o);
  return v;
}
__device__ __forceinline__ u64 wredmax64(u64 v){
  #pragma unroll
  for (int o=32;o>0;o>>=1){ u64 x = __shfl_xor(v, o); v = (x>v)?x:v; }
  return v;
}

// ZL swizzle: j = 8*lane + e  ->  slot (j&7)*64 + ((j>>3) ^ ((j&7)<<2))
__device__ __forceinline__ int zslot(int j){
  return (j&7)*64 + ((j>>3) ^ ((j&7)<<2));
}

#define LOAD8(dst, baseptr) { const float4* _p=(const float4*)(baseptr); \
  float4 _a=_p[0], _b=_p[1]; \
  dst[0]=_a.x; dst[1]=_a.y; dst[2]=_a.z; dst[3]=_a.w; \
  dst[4]=_b.x; dst[5]=_b.y; dst[6]=_b.z; dst[7]=_b.w; }

__global__ void rnnt_init(char* ws){
  // zero rings, flags, agg-epoch, tagged y/u/partials (155648 B = 38912 u32)
  u32* p = (u32*)ws;
  const int stride = blockDim.x * gridDim.x;
  for (int i = blockIdx.x*blockDim.x + threadIdx.x; i < 38912; i += stride) p[i] = 0u;
}

__global__ void __launch_bounds__(NT, 1)
rnnt_decode(const float* __restrict__ h,    const float* __restrict__ embed,
            const float* __restrict__ W_ih, const float* __restrict__ W_hh,
            const float* __restrict__ b_ih, const float* __restrict__ b_hh,
            const float* __restrict__ W_enc,const float* __restrict__ b_enc,
            const float* __restrict__ W_dec,const float* __restrict__ W_out,
            const float* __restrict__ b_out,
            float* __restrict__ out, char* __restrict__ ws)
{
  const int b    = blockIdx.x;
  const int tid  = threadIdx.x;
  const int lane = tid & 63;
  const int w    = tid >> 6;

  u64*  ytag  = (u64*)(ws + WS_Y);
  u64*  utag  = (u64*)(ws + WS_U);
  u64*  ptag  = (u64*)(ws + WS_PART);
  u64*  pkall = (u64*)(ws + WS_PK);
  u64*  saall = (u64*)(ws + WS_SA);
  u32*  done  = (u32*)(ws + WS_DN);
  u32*  aggr  = (u32*)(ws + WS_AGG);
  float* hp   = (float*)(ws + WS_HP);

  __shared__ float smem[8192];                 // 32 KB, multi-purpose
  float* PL = smem;                            // [64][68] partial sums
  float* GL = &smem[4416];                     // gates   (64)
  u64*   R64= (u64*)&smem[4480];               // 4 u64 reduce slots
  float* RF = &smem[4488];                     // 4 float reduce slots
  float* YO = &smem[4492];                     // fresh own-y (16)
  float* ZL = &smem[4544];                     // z, swizzled (512)
  float* PS = &smem[5056];                     // partial-reduce [16][17]

  // ================= setup: hp = h @ W_enc^T + b_enc (rows 8b..8b+7) =========
  {
    float (*lds_h)[EPROJS] = (float(*)[EPROJS])smem;
    #pragma unroll
    for (int r=0;r<8;r++){
      const float4 hv = *(const float4*)(h + (size_t)(8*b + r)*EPROJS + tid*4);
      *(float4*)&lds_h[r][tid*4] = hv;
    }
    __syncthreads();
    for (int p=0;p<2;p++){
      const int j = p*NT + tid;
      float acc[8] = {0,0,0,0,0,0,0,0};
      const float4* wrow = (const float4*)(W_enc + (size_t)j*EPROJS);
      for (int k4=0;k4<EPROJS/4;k4++){
        const float4 wv = wrow[k4];
        #pragma unroll
        for (int t8=0;t8<8;t8++){
          const float4 hv = *(const float4*)&lds_h[t8][k4*4];
          acc[t8] = fmaf(wv.x,hv.x, fmaf(wv.y,hv.y, fmaf(wv.z,hv.z, fmaf(wv.w,hv.w, acc[t8]))));
        }
      }
      const float be = b_enc[j];
      #pragma unroll
      for (int t8=0;t8<8;t8++)
        astoref(&hp[(size_t)(8*b+t8)*JOINT + j], acc[t8] + be);
    }
    asm volatile("s_waitcnt vmcnt(0)" ::: "memory");
    if (tid==0) astoreu32(&done[b], MAGIC);
    __syncthreads();   // smem reuse fence
  }

  // ============================ role: LSTM ===================================
  if (b < N_LSTM){
    const int d = b;
    float wih[16][8], whh[16][8];
    #pragma unroll
    for (int q=0;q<16;q++){
      const int gr = w*DUNITS + 16*d + q;       // wave w = gate type (i,f,g,o)
      LOAD8(wih[q], W_ih + (size_t)gr*EMBED  + lane*8);
      LOAD8(whh[q], W_hh + (size_t)gr*DUNITS + lane*8);
    }
    // W_dec COLUMN slice: thread owns rows 2tid,2tid+1 x cols [16d,16d+16)
    float wdc0[16], wdc1[16];
    {
      const float4* p0 = (const float4*)(W_dec + (size_t)(2*tid)*DUNITS   + 16*d);
      const float4* p1 = (const float4*)(W_dec + (size_t)(2*tid+1)*DUNITS + 16*d);
      #pragma unroll
      for (int k4=0;k4<4;k4++){
        const float4 a = p0[k4];
        wdc0[4*k4+0]=a.x; wdc0[4*k4+1]=a.y; wdc0[4*k4+2]=a.z; wdc0[4*k4+3]=a.w;
        const float4 c = p1[k4];
        wdc1[4*k4+0]=c.x; wdc1[4*k4+1]=c.y; wdc1[4*k4+2]=c.z; wdc1[4*k4+3]=c.w;
      }
    }
    float bias_r = 0.0f;
    if (tid < 64){
      const int gr = (tid>>4)*DUNITS + 16*d + (tid&15);
      bias_r = b_ih[gr] + b_hh[gr];
    }
    // bootstrap: publish tagged y(1) + partial(1)
    float c_st = 0.0f, y_st = 0.0f;
    if (tid < 16){
      const int j = 16*d + tid;
      const float gi = b_ih[j]            + b_hh[j];
      const float gg = b_ih[2*DUNITS + j] + b_hh[2*DUNITS + j];
      const float go = b_ih[3*DUNITS + j] + b_hh[3*DUNITS + j];
      c_st = sigmoidf_(gi)*tanhf(gg);
      y_st = sigmoidf_(go)*tanhf(c_st);
      YO[tid] = y_st;
      astoreu64(&ytag[j], ((u64)1u<<32) | (u64)__float_as_uint(y_st));
    }
    __syncthreads();
    {
      float p0=0.f, p1=0.f;
      #pragma unroll
      for (int k=0;k<16;k++){ p0 = fmaf(wdc0[k], YO[k], p0); p1 = fmaf(wdc1[k], YO[k], p1); }
      u64* up = ptag + (size_t)d*512;
      astoreu64(&up[2*tid],   ((u64)1u<<32) | (u64)__float_as_uint(p0));
      astoreu64(&up[2*tid+1], ((u64)1u<<32) | (u64)__float_as_uint(p1));
    }

    const int jj = tid & 15;       // element offset within our u slice
    const int pp = tid >> 4;       // partial-pair index (p = 2pp, 2pp+1)
    for (int t=0;t<TMAX;t++){
      const u32 g = (u32)(t+1);
      // --- phase A: merged poll of partials(g) slice + y(g), tag==payload ----
      u64 pv0, pv1, yv[8];
      for(;;){
        pv0 = aloadu64(&ptag[(size_t)(2*pp)*512   + 16*d + jj]);
        pv1 = aloadu64(&ptag[(size_t)(2*pp+1)*512 + 16*d + jj]);
        bool ok = ((u32)(pv0>>32)==g) & ((u32)(pv1>>32)==g);
        #pragma unroll
        for (int i=0;i<8;i++){
          yv[i] = aloadu64(&ytag[8*lane + i]);
          ok &= ((u32)(yv[i]>>32) == g);
        }
        if (ok) break;
        __builtin_amdgcn_s_sleep(1);
      }
      float y8[8];
      #pragma unroll
      for (int i=0;i<8;i++) y8[i] = __uint_as_float((u32)yv[i]);
      // --- phase B: LDS-reduce partials -> publish u slice (16 tagged words) -
      PS[jj*17 + pp] = __uint_as_float((u32)pv0) + __uint_as_float((u32)pv1);
      __syncthreads();
      if (tid < 16){
        float s = 0.f;
        #pragma unroll
        for (int k=0;k<16;k++) s += PS[tid*17 + k];
        astoreu64(&utag[16*d + tid], ((u64)g<<32) | (u64)__float_as_uint(s));
      }
      // --- phase C: vp = W_hh @ y (cheap, hidden under pack wait) ------------
      float vp[16];
      #pragma unroll
      for (int q=0;q<16;q++){
        float a=0.f;
        #pragma unroll
        for (int k=0;k<8;k++) a = fmaf(whh[q][k], y8[k], a);
        vp[q] = a;
      }
      // --- phase D: poll packs(g), throttled; argmax + speculative embed -----
      u64 pk = 0;
      {
        const u64* pks = pkall + (g&3)*224;
        for(;;){
          pk = (tid < N_CONS) ? aloadu64(&pks[tid]) : 0;
          const int ok = (tid < N_CONS) ? ((u32)(pk>>48) >= g) : 1;
          if (__all(ok)) break;
          __builtin_amdgcn_s_sleep(1);
        }
      }
      const u64 m = wredmax64(pk);
      if (lane==0) R64[w] = m;
      const int predw = (int)((~(u32)m) & 0xFFFFu);
      float e8[8];
      LOAD8(e8, embed + (size_t)predw*EMBED + 8*lane);
      __syncthreads();
      u64 best = R64[0];
      #pragma unroll
      for (int i=1;i<4;i++){ const u64 x=R64[i]; best = (x>best)?x:best; }
      const int pred = (int)((~(u32)best) & 0xFFFFu);
      const int emitted = (pred != 0);
      if (m != best){                            // wave-uniform mispredict: hot reload
        LOAD8(e8, embed + (size_t)pred*EMBED + 8*lane);
      }
      // --- phase E: gates -> state -> publish y(g+1) + partial(g+1) ----------
      #pragma unroll
      for (int q=0;q<16;q++){
        float a = vp[q];
        #pragma unroll
        for (int k=0;k<8;k++) a = fmaf(wih[q][k], e8[k], a);
        PL[(w*16+q)*68 + lane] = a;
      }
      __syncthreads();
      if (tid < 64){
        const float* row = &PL[tid*68];
        float s = bias_r;
        #pragma unroll
        for (int k4=0;k4<16;k4++){
          const float4 v4 = *(const float4*)&row[4*k4];
          s += v4.x + v4.y + v4.z + v4.w;
        }
        GL[tid] = s;
      }
      __syncthreads();
      if (tid < 16){
        const float gi=GL[tid], gf=GL[16+tid], gg=GL[32+tid], go=GL[48+tid];
        const float cn = sigmoidf_(gf)*c_st + sigmoidf_(gi)*tanhf(gg);
        const float yn = sigmoidf_(go)*tanhf(cn);
        if (emitted){ c_st = cn; y_st = yn; }
        YO[tid] = y_st;
        if (t < TMAX-1)
          astoreu64(&ytag[16*d + tid], ((u64)(g+1)<<32) | (u64)__float_as_uint(y_st));
      }
      __syncthreads();                           // YO visible to all waves
      if (t < TMAX-1){
        float p0=0.f, p1=0.f;
        #pragma unroll
        for (int k=0;k<16;k++){ p0 = fmaf(wdc0[k], YO[k], p0); p1 = fmaf(wdc1[k], YO[k], p1); }
        u64* up = ptag + (size_t)d*512;
        astoreu64(&up[2*tid],   ((u64)(g+1)<<32) | (u64)__float_as_uint(p0));
        astoreu64(&up[2*tid+1], ((u64)(g+1)<<32) | (u64)__float_as_uint(p1));
      }
    }
  }
  // ============================ role: CONSUMER ===============================
  else if (b < AGG_B){
    const int cb = b - CONS0;
    int rowstart, rowcnt;
    if (cb < 188){ rowstart = cb*45;                 rowcnt = 45; }
    else         { rowstart = 8460 + (cb-188)*44;    rowcnt = 44; }
    float wout[12][8];
    #pragma unroll
    for (int q=0;q<12;q++){
      const int s = 12*w + q;
      if (s < rowcnt){
        LOAD8(wout[q], W_out + (size_t)(rowstart+s)*JOINT + lane*8);
      } else {
        #pragma unroll
        for (int k=0;k<8;k++) wout[q][k]=0.f;
      }
    }
    float my_bo = 0.f; int my_row = 0; bool my_val = false;
    if (tid < rowcnt){ my_val = true; my_row = rowstart + tid; my_bo = b_out[my_row]; }
    const u32* agrep = &aggr[(cb&7)*32];

    // wait for all hp writers
    for(;;){
      const u32 dv = aloadu32(&done[tid]);
      if (__all(dv == MAGIC)) break;
      __builtin_amdgcn_s_sleep(2);
    }
    __syncthreads();

    const int j0 = 2*tid, j1 = 2*tid+1;
    const int s0 = zslot(j0), s1 = zslot(j1);
    for (int t=0;t<TMAX;t++){
      const u32 g = (u32)(t+1);
      // prefetch hp pair (off critical path)
      const float2 h2 = *(const float2*)(hp + (size_t)t*JOINT + j0);
      // --- poll OWN two tagged u words: detect == payload, throttled ---------
      u64 ua, ub2;
      for(;;){
        ua  = aloadu64(&utag[j0]);
        ub2 = aloadu64(&utag[j1]);
        if ( (((u32)(ua>>32))==g) & (((u32)(ub2>>32))==g) ) break;
        __builtin_amdgcn_s_sleep(1);
      }
      ZL[s0] = tanhf(h2.x + __uint_as_float((u32)ua));
      ZL[s1] = tanhf(h2.y + __uint_as_float((u32)ub2));
      __syncthreads();
      float z8[8];
      #pragma unroll
      for (int e=0;e<8;e++) z8[e] = ZL[e*64 + (lane ^ (e<<2))];   // z[8*lane+e]
      #pragma unroll
      for (int q=0;q<12;q++){
        float a=0.f;
        #pragma unroll
        for (int k=0;k<8;k++) a = fmaf(wout[q][k], z8[k], a);
        PL[(12*w+q)*68 + lane] = a;
      }
      __syncthreads();
      u64 key = 0; float lg = 0.f;
      if (tid < 48){
        const float* row = &PL[tid*68];
        float s = my_bo;
        #pragma unroll
        for (int k4=0;k4<16;k4++){
          const float4 v4 = *(const float4*)&row[4*k4];
          s += v4.x + v4.y + v4.z + v4.w;
        }
        lg = s;
        if (my_val) key = ((u64)ordbits(lg)<<16) | (u64)(0xFFFFu & ~(u32)my_row);
      }
      if (w == 0){
        const u64 bk = wredmax64(key);
        const float mw = unordbits((u32)(bk>>16));
        const float e  = my_val ? __expf(lg - mw) : 0.f;
        const float sw = wredsum(e);
        if (lane == 0){
          // aggregator lead-gate: ring depth 4, keep lead <= 3 (never taken
          // in steady state; prevents ring lap -> aggregator livelock)
          while ((int)(g - aloadu32(agrep)) > 3) __builtin_amdgcn_s_sleep(2);
          astoreu64(&saall[(g&3)*224 + cb], ((u64)g<<32) | (u64)__float_as_uint(sw));
          astoreu64(&pkall[(g&3)*224 + cb], ((u64)g<<48) | bk);
        }
      }
      // PL/ZL reuse at iter g+1 is gated by the u(g+1) poll, which transitively
      // requires this block's pack(g) -> wave-0 PL reads complete. No barrier.
    }
  }
  // ============================ role: AGGREGATOR =============================
  else {
    float score = 0.0f;
    for (int t=0;t<TMAX;t++){
      const u32 g = (u32)(t+1);
      const u64* pks = pkall + (g&3)*224;
      const u64* sas = saall + (g&3)*224;
      u64 pk=0, sa=0;
      for(;;){
        if (tid < N_CONS){ pk = aloadu64(&pks[tid]); sa = aloadu64(&sas[tid]); }
        const int ok = (tid < N_CONS) ? (((u32)(pk>>48)==g) & (((u32)(sa>>32))==g)) : 1;
        if (__all(ok)) break;
        __builtin_amdgcn_s_sleep(2);
      }
      { u64 m = wredmax64(pk); if (lane==0) R64[w]=m; }
      __syncthreads();
      u64 best = R64[0];
      #pragma unroll
      for (int i=1;i<4;i++){ const u64 x=R64[i]; best = (x>best)?x:best; }
      const float mstar = unordbits((u32)(best>>16));
      float term = (tid < N_CONS) ?
        __uint_as_float((u32)sa) * __expf(unordbits((u32)(pk>>16)) - mstar) : 0.f;
      term = wredsum(term);
      if (lane==0) RF[w] = term;
      __syncthreads();
      if (tid==0){
        const float S = RF[0]+RF[1]+RF[2]+RF[3];
        const int pred = (int)((~(u32)best) & 0xFFFFu);
        if (pred != 0) score += -logf(S);
        out[t] = (float)pred;
      }
      __syncthreads();   // protect R64/RF for next iteration
      if (tid < 8) astoreu32(&aggr[tid*32], g);  // publish progress (lead-gate)
    }
    if (tid==0) out[TMAX] = score;
  }
}

extern "C" void kernel_launch(void* const* d_in, const int* in_sizes, int n_in,
                              void* d_out, int out_size, void* d_ws, size_t ws_size,
                              hipStream_t stream)
{
  const float* h     = (const float*)d_in[0];
  const float* embed = (const float*)d_in[1];
  const float* W_ih  = (const float*)d_in[2];
  const float* W_hh  = (const float*)d_in[3];
  const float* b_ih  = (const float*)d_in[4];
  const float* b_hh  = (const float*)d_in[5];
  const float* W_enc = (const float*)d_in[6];
  const float* b_enc = (const float*)d_in[7];
  const float* W_dec = (const float*)d_in[8];
  const float* W_out = (const float*)d_in[9];
  const float* b_out = (const float*)d_in[10];
  float* out = (float*)d_out;
  char* ws = (char*)d_ws;

  hipLaunchKernelGGL(rnnt_init, dim3(32), dim3(NT), 0, stream, ws);
  hipLaunchKernelGGL(rnnt_decode, dim3(NB), dim3(NT), 0, stream,
                     h, embed, W_ih, W_hh, b_ih, b_hh, W_enc, b_enc, W_dec, W_out, b_out,
                     out, ws);
}

// Round 7
// 16711.568 us; speedup vs baseline: 1.2797x; 1.0594x over previous
//
#include <hip/hip_runtime.h>
#include <stdint.h>

typedef unsigned long long u64;
typedef uint32_t u32;

#define NB     256
#define NT     256
#define TMAX   2048
#define EPROJS 1024
#define DUNITS 512
#define EMBED  512
#define JOINT  512
#define ODIM   10000

#define N_LSTM 32          // blocks 0..31: LSTM + replica-atomic u producers
#define CONS0  32          // blocks 32..254: consumers (W_out)
#define N_CONS 223
#define AGG_B  255         // block 255: score/token aggregator
#define MAGIC  0xD07ED07Eu

// workspace layout (bytes); first 54272 B zeroed by rnnt_init
// total = 54272 + 4 MB = 4,248,576 B (< r3-proven 4,358,144)
#define WS_PK   0          // u64[4][224]   consumer packs, 4-deep ring (tag bits 48+)
#define WS_SA   7168       // u64[4][224]   consumer sum-exp, 4-deep ring (tag bits 32+)
#define WS_DN   14336      // u32[256]      setup-done flags
#define WS_AGG  15360      // u32 aggregator-epoch replicas [8] @ 128B stride
#define WS_CNT  16384      // u32 u-epoch counter replicas [8] @ 128B stride
#define WS_Y    17408      // u64[512]      tagged y words (epoch<<32 | f32)
#define WS_U    21504      // float[2][8][512] u replicas, parity-2 (32 KB)
#define WS_HP   54272      // float[2048][512] h_proj  (4 MB)

__device__ __forceinline__ float aloadf(const float* p){
  return __hip_atomic_load(p, __ATOMIC_RELAXED, __HIP_MEMORY_SCOPE_AGENT);
}
__device__ __forceinline__ void astoref(float* p, float v){
  __hip_atomic_store(p, v, __ATOMIC_RELAXED, __HIP_MEMORY_SCOPE_AGENT);
}
__device__ __forceinline__ u64 aloadu64(const u64* p){
  return __hip_atomic_load(p, __ATOMIC_RELAXED, __HIP_MEMORY_SCOPE_AGENT);
}
__device__ __forceinline__ void astoreu64(u64* p, u64 v){
  __hip_atomic_store(p, v, __ATOMIC_RELAXED, __HIP_MEMORY_SCOPE_AGENT);
}
__device__ __forceinline__ u32 aloadu32(const u32* p){
  return __hip_atomic_load(p, __ATOMIC_RELAXED, __HIP_MEMORY_SCOPE_AGENT);
}
__device__ __forceinline__ void astoreu32(u32* p, u32 v){
  __hip_atomic_store(p, v, __ATOMIC_RELAXED, __HIP_MEMORY_SCOPE_AGENT);
}

__device__ __forceinline__ u32 ordbits(float f){
  u32 u = __float_as_uint(f);
  return (u & 0x80000000u) ? ~u : (u | 0x80000000u);
}
__device__ __forceinline__ float unordbits(u32 o){
  u32 u = (o & 0x80000000u) ? (o & 0x7fffffffu) : ~o;
  return __uint_as_float(u);
}
__device__ __forceinline__ float sigmoidf_(float x){ return 1.0f/(1.0f+expf(-x)); }

__device__ __forceinline__ float wredsum(float v){
  #pragma unroll
  for (int o=32;o>0;o>>=1) v += __shfl_xor(v, o);
  return v;
}
__device__ __forceinline__ u64 wredmax64(u64 v){
  #pragma unroll
  for (int o=32;o>0;o>>=1){ u64 x = __shfl_xor(v, o); v = (x>v)?x:v; }
  return v;
}

// swizzled 512-float LDS stage: j -> (j&7)*64 + ((j>>3) ^ ((j&7)<<2))
// write (j=2tid,2tid+1): <=2-way alias; read j=8*lane+e: conflict-free.
__device__ __forceinline__ int zslot(int j){
  return (j&7)*64 + ((j>>3) ^ ((j&7)<<2));
}

#define LOAD8(dst, baseptr) { const float4* _p=(const float4*)(baseptr); \
  float4 _a=_p[0], _b=_p[1]; \
  dst[0]=_a.x; dst[1]=_a.y; dst[2]=_a.z; dst[3]=_a.w; \
  dst[4]=_b.x; dst[5]=_b.y; dst[6]=_b.z; dst[7]=_b.w; }

__global__ void rnnt_init(char* ws){
  // zero rings, flags, counters, tagged y, u replicas (54272 B = 13568 u32)
  u32* p = (u32*)ws;
  const int stride = blockDim.x * gridDim.x;
  for (int i = blockIdx.x*blockDim.x + threadIdx.x; i < 13568; i += stride) p[i] = 0u;
}

__global__ void __launch_bounds__(NT, 1)
rnnt_decode(const float* __restrict__ h,    const float* __restrict__ embed,
            const float* __restrict__ W_ih, const float* __restrict__ W_hh,
            const float* __restrict__ b_ih, const float* __restrict__ b_hh,
            const float* __restrict__ W_enc,const float* __restrict__ b_enc,
            const float* __restrict__ W_dec,const float* __restrict__ W_out,
            const float* __restrict__ b_out,
            float* __restrict__ out, char* __restrict__ ws)
{
  const int b    = blockIdx.x;
  const int tid  = threadIdx.x;
  const int lane = tid & 63;
  const int w    = tid >> 6;

  u64*   ytag = (u64*)(ws + WS_Y);
  float* ubuf = (float*)(ws + WS_U);      // [2][8][512]
  u64*  pkall = (u64*)(ws + WS_PK);
  u64*  saall = (u64*)(ws + WS_SA);
  u32*  done  = (u32*)(ws + WS_DN);
  u32*  aggr  = (u32*)(ws + WS_AGG);
  u32*  cnt   = (u32*)(ws + WS_CNT);
  float* hp   = (float*)(ws + WS_HP);

  __shared__ float smem[8192];                 // 32 KB, multi-purpose
  float* PL = smem;                            // [64][68] partial sums
  float* GL = &smem[4416];                     // gates   (64)
  u64*   R64= (u64*)&smem[4480];               // 4 u64 reduce slots
  float* RF = &smem[4488];                     // 4 float reduce slots
  float* YO = &smem[4492];                     // fresh own-y (16)
  float* SL = &smem[4544];                     // swizzled 512-float stage (y or z)

  // ================= setup: hp = h @ W_enc^T + b_enc (rows 8b..8b+7) =========
  {
    float (*lds_h)[EPROJS] = (float(*)[EPROJS])smem;
    #pragma unroll
    for (int r=0;r<8;r++){
      const float4 hv = *(const float4*)(h + (size_t)(8*b + r)*EPROJS + tid*4);
      *(float4*)&lds_h[r][tid*4] = hv;
    }
    __syncthreads();
    for (int p=0;p<2;p++){
      const int j = p*NT + tid;
      float acc[8] = {0,0,0,0,0,0,0,0};
      const float4* wrow = (const float4*)(W_enc + (size_t)j*EPROJS);
      for (int k4=0;k4<EPROJS/4;k4++){
        const float4 wv = wrow[k4];
        #pragma unroll
        for (int t8=0;t8<8;t8++){
          const float4 hv = *(const float4*)&lds_h[t8][k4*4];
          acc[t8] = fmaf(wv.x,hv.x, fmaf(wv.y,hv.y, fmaf(wv.z,hv.z, fmaf(wv.w,hv.w, acc[t8]))));
        }
      }
      const float be = b_enc[j];
      #pragma unroll
      for (int t8=0;t8<8;t8++)
        astoref(&hp[(size_t)(8*b+t8)*JOINT + j], acc[t8] + be);
    }
    asm volatile("s_waitcnt vmcnt(0)" ::: "memory");
    if (tid==0) astoreu32(&done[b], MAGIC);
    __syncthreads();   // smem reuse fence
  }

  // ============================ role: LSTM ===================================
  if (b < N_LSTM){
    const int d = b;
    float wih[16][8], whh[16][8];
    #pragma unroll
    for (int q=0;q<16;q++){
      const int gr = w*DUNITS + 16*d + q;       // wave w = gate type (i,f,g,o)
      LOAD8(wih[q], W_ih + (size_t)gr*EMBED  + lane*8);
      LOAD8(whh[q], W_hh + (size_t)gr*DUNITS + lane*8);
    }
    // W_dec COLUMN slice: thread owns rows 2tid,2tid+1 x cols [16d,16d+16)
    float wdc0[16], wdc1[16];
    {
      const float4* p0 = (const float4*)(W_dec + (size_t)(2*tid)*DUNITS   + 16*d);
      const float4* p1 = (const float4*)(W_dec + (size_t)(2*tid+1)*DUNITS + 16*d);
      #pragma unroll
      for (int k4=0;k4<4;k4++){
        const float4 a = p0[k4];
        wdc0[4*k4+0]=a.x; wdc0[4*k4+1]=a.y; wdc0[4*k4+2]=a.z; wdc0[4*k4+3]=a.w;
        const float4 c = p1[k4];
        wdc1[4*k4+0]=c.x; wdc1[4*k4+1]=c.y; wdc1[4*k4+2]=c.z; wdc1[4*k4+3]=c.w;
      }
    }
    float bias_r = 0.0f;
    if (tid < 64){
      const int gr = (tid>>4)*DUNITS + 16*d + (tid&15);
      bias_r = b_ih[gr] + b_hh[gr];
    }
    // bootstrap state -> publish tagged y(1) + replica-add u(1) (parity 1)
    float c_st = 0.0f, y_st = 0.0f;
    if (tid < 16){
      const int j = 16*d + tid;
      const float gi = b_ih[j]            + b_hh[j];
      const float gg = b_ih[2*DUNITS + j] + b_hh[2*DUNITS + j];
      const float go = b_ih[3*DUNITS + j] + b_hh[3*DUNITS + j];
      c_st = sigmoidf_(gi)*tanhf(gg);
      y_st = sigmoidf_(go)*tanhf(c_st);
      YO[tid] = y_st;
      astoreu64(&ytag[j], ((u64)1u<<32) | (u64)__float_as_uint(y_st));
    }
    __syncthreads();
    {
      float p0=0.f, p1=0.f;
      #pragma unroll
      for (int k=0;k<16;k++){ p0 = fmaf(wdc0[k], YO[k], p0); p1 = fmaf(wdc1[k], YO[k], p1); }
      float* up = ubuf + 1*4096 + (d&7)*512;    // parity 1, replica d&7
      atomicAdd(&up[2*tid],   p0);
      atomicAdd(&up[2*tid+1], p1);
    }
    asm volatile("s_waitcnt vmcnt(0)" ::: "memory");
    __syncthreads();
    if (tid < 8) atomicAdd(&cnt[tid*32], 1u);

    for (int t=0;t<TMAX;t++){
      const u32 g = (u32)(t+1);
      // --- poll y(g): tagged words, barrier-coupled (r1-stable pattern) ------
      u64 ya, yb;
      for(;;){
        ya = aloadu64(&ytag[2*tid]); yb = aloadu64(&ytag[2*tid+1]);
        const int ok = ((u32)(ya>>32)==g) & ((u32)(yb>>32)==g);
        if (__syncthreads_and(ok)) break;
      }
      SL[zslot(2*tid)]   = __uint_as_float((u32)ya);
      SL[zslot(2*tid+1)] = __uint_as_float((u32)yb);
      __syncthreads();
      float y8[8];
      #pragma unroll
      for (int e=0;e<8;e++) y8[e] = SL[e*64 + (lane ^ (e<<2))];   // y[8*lane+e]
      // --- vp = W_hh @ y partials (off critical path) ---
      float vp[16];
      #pragma unroll
      for (int q=0;q<16;q++){
        float a=0.f;
        #pragma unroll
        for (int k=0;k<8;k++) a = fmaf(whh[q][k], y8[k], a);
        vp[q] = a;
      }
      // --- poll packs(g), barrier-coupled ---
      u64 pk = 0;
      for(;;){
        if (tid < N_CONS) pk = aloadu64(&pkall[(g&3)*224 + tid]);
        const int ok = (tid < N_CONS) ? ((u32)(pk>>48) >= g) : 1;
        if (__syncthreads_and(ok)) break;
      }
      const u64 m = wredmax64(pk);
      if (lane==0) R64[w] = m;
      // speculative embed prefetch of this wave's candidate (direct, no LDS)
      const int predw = (int)((~(u32)m) & 0xFFFFu);
      float e8[8];
      LOAD8(e8, embed + (size_t)predw*EMBED + 8*lane);
      __syncthreads();
      u64 best = R64[0];
      #pragma unroll
      for (int i=1;i<4;i++){ const u64 x=R64[i]; best = (x>best)?x:best; }
      const int pred = (int)((~(u32)best) & 0xFFFFu);
      const int emitted = (pred != 0);
      if (m != best){                            // wave-uniform mispredict: hot reload
        LOAD8(e8, embed + (size_t)pred*EMBED + 8*lane);
      }
      // recycle just-consumed u parity buffer (for epoch g+2): 128 floats/block
      if (tid < 64){
        u64* uz = (u64*)(ubuf + (g&1)*4096 + (d&7)*512) + (d>>3)*64;
        astoreu64(&uz[tid], 0ull);
      }
      // --- gates ---
      #pragma unroll
      for (int q=0;q<16;q++){
        float a = vp[q];
        #pragma unroll
        for (int k=0;k<8;k++) a = fmaf(wih[q][k], e8[k], a);
        PL[(w*16+q)*68 + lane] = a;
      }
      __syncthreads();
      if (tid < 64){
        const float* row = &PL[tid*68];
        float s = bias_r;
        #pragma unroll
        for (int k4=0;k4<16;k4++){
          const float4 v4 = *(const float4*)&row[4*k4];
          s += v4.x + v4.y + v4.z + v4.w;
        }
        GL[tid] = s;
      }
      __syncthreads();
      if (tid < 16){
        const float gi=GL[tid], gf=GL[16+tid], gg=GL[32+tid], go=GL[48+tid];
        const float cn = sigmoidf_(gf)*c_st + sigmoidf_(gi)*tanhf(gg);
        const float yn = sigmoidf_(go)*tanhf(cn);
        if (emitted){ c_st = cn; y_st = yn; }
        YO[tid] = y_st;
        if (t < TMAX-1)
          astoreu64(&ytag[16*d + tid], ((u64)(g+1)<<32) | (u64)__float_as_uint(y_st));
      }
      __syncthreads();                           // YO visible to all waves
      if (t < TMAX-1){
        float p0=0.f, p1=0.f;
        #pragma unroll
        for (int k=0;k<16;k++){ p0 = fmaf(wdc0[k], YO[k], p0); p1 = fmaf(wdc1[k], YO[k], p1); }
        float* up = ubuf + ((g+1)&1)*4096 + (d&7)*512;
        atomicAdd(&up[2*tid],   p0);
        atomicAdd(&up[2*tid+1], p1);
      }
      asm volatile("s_waitcnt vmcnt(0)" ::: "memory");
      __syncthreads();
      if (t < TMAX-1 && tid < 8) atomicAdd(&cnt[tid*32], 1u);
    }
  }
  // ============================ role: CONSUMER ===============================
  else if (b < AGG_B){
    const int cb = b - CONS0;
    int rowstart, rowcnt;
    if (cb < 188){ rowstart = cb*45;                 rowcnt = 45; }
    else         { rowstart = 8460 + (cb-188)*44;    rowcnt = 44; }
    float wout[12][8];
    #pragma unroll
    for (int q=0;q<12;q++){
      const int s = 12*w + q;
      if (s < rowcnt){
        LOAD8(wout[q], W_out + (size_t)(rowstart+s)*JOINT + lane*8);
      } else {
        #pragma unroll
        for (int k=0;k<8;k++) wout[q][k]=0.f;
      }
    }
    float my_bo = 0.f; int my_row = 0; bool my_val = false;
    if (tid < rowcnt){ my_val = true; my_row = rowstart + tid; my_bo = b_out[my_row]; }
    const u32* agrep = &aggr[(cb&7)*32];

    // wait for all hp writers (r1-exact)
    for(;;){
      const int ok = (aloadu32(&done[tid]) == MAGIC);
      if (__syncthreads_and(ok)) break;
    }

    const u32* cp = &cnt[(cb&7)*32];
    const int j0 = 2*tid, j1 = 2*tid+1;
    const int s0 = zslot(j0), s1 = zslot(j1);
    for (int t=0;t<TMAX;t++){
      const u32 g = (u32)(t+1);
      // prefetch hp pair before the wait
      const float2 h2 = *(const float2*)(hp + (size_t)t*JOINT + j0);
      if (tid==0){ while (aloadu32(cp) < 32u*g) {} }
      __syncthreads();
      // sum the 8 u replicas for elements j0, j1 (pipelined LLC loads)
      float u0 = 0.f, u1 = 0.f;
      {
        const u64* ub64 = (const u64*)(ubuf + (g&1)*4096) + tid;
        u64 v[8];
        #pragma unroll
        for (int r=0;r<8;r++) v[r] = aloadu64(ub64 + r*256);
        #pragma unroll
        for (int r=0;r<8;r++){
          u0 += __uint_as_float((u32)v[r]);
          u1 += __uint_as_float((u32)(v[r]>>32));
        }
      }
      SL[s0] = tanhf(h2.x + u0);
      SL[s1] = tanhf(h2.y + u1);
      __syncthreads();
      float z8[8];
      #pragma unroll
      for (int e=0;e<8;e++) z8[e] = SL[e*64 + (lane ^ (e<<2))];   // z[8*lane+e]
      #pragma unroll
      for (int q=0;q<12;q++){
        float a=0.f;
        #pragma unroll
        for (int k=0;k<8;k++) a = fmaf(wout[q][k], z8[k], a);
        PL[(12*w+q)*68 + lane] = a;
      }
      __syncthreads();
      u64 key = 0; float lg = 0.f;
      if (tid < 48){
        const float* row = &PL[tid*68];
        float s = my_bo;
        #pragma unroll
        for (int k4=0;k4<16;k4++){
          const float4 v4 = *(const float4*)&row[4*k4];
          s += v4.x + v4.y + v4.z + v4.w;
        }
        lg = s;
        if (my_val) key = ((u64)ordbits(lg)<<16) | (u64)(0xFFFFu & ~(u32)my_row);
      }
      if (w == 0){
        const u64 bk = wredmax64(key);
        const float mw = unordbits((u32)(bk>>16));
        const float e  = my_val ? __expf(lg - mw) : 0.f;
        const float sw = wredsum(e);
        if (lane == 0){
          // lead-gate: keep <=3 epochs ahead of aggregator (ring depth 4)
          while ((int)(g - aloadu32(agrep)) > 3) __builtin_amdgcn_s_sleep(2);
          astoreu64(&saall[(g&3)*224 + cb], ((u64)g<<32) | (u64)__float_as_uint(sw));
          astoreu64(&pkall[(g&3)*224 + cb], ((u64)g<<48) | bk);
        }
      }
      __syncthreads();   // PL/SL reuse fence
    }
  }
  // ============================ role: AGGREGATOR =============================
  else {
    float score = 0.0f;
    for (int t=0;t<TMAX;t++){
      const u32 g = (u32)(t+1);
      const u64* pks = pkall + (g&3)*224;
      const u64* sas = saall + (g&3)*224;
      u64 pk=0, sa=0;
      for(;;){
        if (tid < N_CONS){ pk = aloadu64(&pks[tid]); sa = aloadu64(&sas[tid]); }
        const int ok = (tid < N_CONS) ? (((u32)(pk>>48)==g) & (((u32)(sa>>32))==g)) : 1;
        if (__syncthreads_and(ok)) break;
      }
      { u64 m = wredmax64(pk); if (lane==0) R64[w]=m; }
      __syncthreads();
      u64 best = R64[0];
      #pragma unroll
      for (int i=1;i<4;i++){ const u64 x=R64[i]; best = (x>best)?x:best; }
      const float mstar = unordbits((u32)(best>>16));
      float term = (tid < N_CONS) ?
        __uint_as_float((u32)sa) * __expf(unordbits((u32)(pk>>16)) - mstar) : 0.f;
      term = wredsum(term);
      if (lane==0) RF[w] = term;
      __syncthreads();
      if (tid==0){
        const float S = RF[0]+RF[1]+RF[2]+RF[3];
        const int pred = (int)((~(u32)best) & 0xFFFFu);
        if (pred != 0) score += -logf(S);
        out[t] = (float)pred;
      }
      __syncthreads();   // protect R64/RF for next iteration
      if (tid < 8) astoreu32(&aggr[tid*32], g);  // publish progress (lead-gate)
    }
    if (tid==0) out[TMAX] = score;
  }
}

extern "C" void kernel_launch(void* const* d_in, const int* in_sizes, int n_in,
                              void* d_out, int out_size, void* d_ws, size_t ws_size,
                              hipStream_t stream)
{
  const float* h     = (const float*)d_in[0];
  const float* embed = (const float*)d_in[1];
  const float* W_ih  = (const float*)d_in[2];
  const float* W_hh  = (const float*)d_in[3];
  const float* b_ih  = (const float*)d_in[4];
  const float* b_hh  = (const float*)d_in[5];
  const float* W_enc = (const float*)d_in[6];
  const float* b_enc = (const float*)d_in[7];
  const float* W_dec = (const float*)d_in[8];
  const float* W_out = (const float*)d_in[9];
  const float* b_out = (const float*)d_in[10];
  float* out = (float*)d_out;
  char* ws = (char*)d_ws;

  hipLaunchKernelGGL(rnnt_init, dim3(32), dim3(NT), 0, stream, ws);
  hipLaunchKernelGGL(rnnt_decode, dim3(NB), dim3(NT), 0, stream,
                     h, embed, W_ih, W_hh, b_ih, b_hh, W_enc, b_enc, W_dec, W_out, b_out,
                     out, ws);
}